// Round 19
// baseline (954.103 us; speedup 1.0000x reference)
//
#include <hip/hip_runtime.h>
#include <math.h>

#define BATCH 4
#define NP    2048
#define KNNK  20
#define DEMB  512
#define NH    4
#define DHD   128

typedef __attribute__((ext_vector_type(8))) short bf16x8;
typedef __attribute__((ext_vector_type(4))) float f32x4;

__device__ __forceinline__ unsigned short f2b(float f) {
  unsigned u = __builtin_bit_cast(unsigned, f);
  u += 0x7FFF + ((u >> 16) & 1);
  return (unsigned short)(u >> 16);
}
__device__ __forceinline__ float b2f(unsigned short u) {
  unsigned v = ((unsigned)u) << 16;
  return __builtin_bit_cast(float, v);
}

__device__ __forceinline__ void gload_lds16(const void* g, void* l) {
  __builtin_amdgcn_global_load_lds(
      (const __attribute__((address_space(1))) unsigned int*)g,
      (__attribute__((address_space(3))) unsigned int*)l, 16, 0, 0);
}

// ---------------------------------------------------------------- merged kNN + weight-conv (block-range split)
__global__ __launch_bounds__(256) void convknn_kernel(
    const float* __restrict__ x0, const float* __restrict__ x1,
    int* __restrict__ io0, int* __restrict__ io1,
    const float* __restrict__ s0, const float* __restrict__ s1,
    const float* __restrict__ s2, const float* __restrict__ s3,
    const float* __restrict__ s4, const float* __restrict__ s5,
    const float* __restrict__ s6,
    unsigned short* __restrict__ d0, unsigned short* __restrict__ d1,
    unsigned short* __restrict__ d2, unsigned short* __restrict__ d3,
    unsigned short* __restrict__ d4, unsigned short* __restrict__ d5,
    unsigned short* __restrict__ d6, float* __restrict__ vpot, int* __restrict__ scnt) {
  __shared__ float xs0[NP], xs1[NP], xs2[NP];
  if (blockIdx.x >= 4096) {
    // ---- weight conversion path (blocks 4096..5744)
    int i4 = ((blockIdx.x - 4096) * 256 + threadIdx.x) * 4;
    const float* src; unsigned short* dst; int off;
    if      (i4 < 262144)  { src = s0; dst = d0; off = i4; }
    else if (i4 < 524288)  { src = s1; dst = d1; off = i4 - 262144; }
    else if (i4 < 786432)  { src = s2; dst = d2; off = i4 - 524288; }
    else if (i4 < 1048576) { src = s3; dst = d3; off = i4 - 786432; }
    else if (i4 < 1572864) { src = s4; dst = d4; off = i4 - 1048576; }
    else if (i4 < 1581056) { src = s5; dst = d5; off = i4 - 1572864; }
    else if (i4 < 1679360) { src = s6; dst = d6; off = i4 - 1581056; }
    else if (i4 < 1687552) {
      off = i4 - 1679360;
      *(float4*)(vpot + off) = (float4){0.f, 0.f, 0.f, 0.f};
      return;
    } else if (i4 < 1687584) {
      int off2 = i4 - 1687552;
      *(int4*)(scnt + off2) = (int4){0, 0, 0, 0};
      return;
    } else return;
    float4 v = *(const float4*)(src + off);
    dst[off] = f2b(v.x); dst[off + 1] = f2b(v.y);
    dst[off + 2] = f2b(v.z); dst[off + 3] = f2b(v.w);
    return;
  }
  // ---- kNN path (blocks 0..4095)
  int which = blockIdx.x >> 11;
  int inner = blockIdx.x & 2047;
  const float* x = which ? x1 : x0;
  int* idx_out = which ? io1 : io0;
  int b = inner >> 9;
  int p0 = (inner & 511) * 4;
  int t = threadIdx.x, w = t >> 6, lane = t & 63;
  const float* xb = x + (size_t)b * 3 * NP;
  for (int m = t; m < NP; m += 256) {
    xs0[m] = xb[m]; xs1[m] = xb[NP + m]; xs2[m] = xb[2 * NP + m];
  }
  __syncthreads();
  int n = p0 + w;
  float c0 = xs0[n], c1 = xs1[n], c2 = xs2[n];
  float xxn = c0 * c0 + c1 * c1 + c2 * c2;
  float nd[32];
#pragma unroll
  for (int i = 0; i < 32; ++i) {
    int m = i * 64 + lane;
    float a0 = xs0[m], a1 = xs1[m], a2 = xs2[m];
    nd[i] = 2.f * (c0 * a0 + c1 * a1 + c2 * a2) - xxn - (a0 * a0 + a1 * a1 + a2 * a2);
  }
  unsigned sel = 0u;
  int* orow = idx_out + ((size_t)b * NP + n) * KNNK;
  for (int it = 0; it < KNNK; ++it) {
    float bv = -INFINITY; int bi = 0x7fffffff;
#pragma unroll
    for (int i = 0; i < 32; ++i) {
      float v = ((sel >> i) & 1u) ? -INFINITY : nd[i];
      if (v > bv) { bv = v; bi = i * 64 + lane; }
    }
#pragma unroll
    for (int s = 1; s < 64; s <<= 1) {
      float ov = __shfl_xor(bv, s);
      int oi = __shfl_xor(bi, s);
      if (ov > bv || (ov == bv && oi < bi)) { bv = ov; bi = oi; }
    }
    if (lane == 0) orow[it] = bi;
    if (lane == (bi & 63)) sel |= (1u << (bi >> 6));
  }
}

// ---------------------------------------------------------------- fused GAC (merged src/tgt)
__global__ __launch_bounds__(256) void gac4_kernel(
    const float* __restrict__ x0, const float* __restrict__ x1,
    const int* __restrict__ io0, const int* __restrict__ io1,
    const float* __restrict__ w1, const float* __restrict__ s1, const float* __restrict__ b1,
    const unsigned short* __restrict__ w2b, const float* __restrict__ s2,
    const float* __restrict__ b2, unsigned short* __restrict__ xcg_all) {
  __shared__ __align__(16) float w1p[448];
  __shared__ float s1s[64], b1s[64];
  __shared__ float g[4][6][20];
  __shared__ __align__(16) float h1f[4][20][65];
  __shared__ __align__(16) unsigned short h1b[4 * 2048];
  int which = blockIdx.x >> 11;
  int inner = blockIdx.x & 2047;
  const float* x = which ? x1 : x0;
  const int* idx = which ? io1 : io0;
  unsigned short* xcg = xcg_all + (size_t)which * BATCH * NP * 192;
  int t = threadIdx.x, w = t >> 6, lane = t & 63;
  int lr = lane & 15, lg = lane >> 4;
  int b = inner >> 9;
  int n0g = (inner & 511) * 4;
  int pbase = b * NP + n0g;
  const float* xb = x + (size_t)b * 3 * NP;

  for (int i = t; i < 384; i += 256) { int o = i / 6, c = i % 6; w1p[o * 7 + c] = w1[i]; }
  if (t < 64) { s1s[t] = s1[t]; b1s[t] = b1[t]; }
  if (t < 80) {
    int p = t / 20, k = t % 20;
    int n = n0g + p;
    int j = idx[((size_t)b * NP + n) * KNNK + k];
    float c0 = xb[n], c1 = xb[NP + n], c2 = xb[2 * NP + n];
    g[p][0][k] = xb[j] - c0; g[p][1][k] = xb[NP + j] - c1; g[p][2][k] = xb[2 * NP + j] - c2;
    g[p][3][k] = c0; g[p][4][k] = c1; g[p][5][k] = c2;
  }
  for (int i = t; i < 4 * 12 * 32; i += 256) {
    int p = i / 384, rem = i % 384;
    ((unsigned*)h1b)[p * 1024 + (20 + rem / 32) * 32 + (rem & 31)] = 0u;
  }
  __syncthreads();

#pragma unroll
  for (int pass = 0; pass < 20; ++pass) {
    int item = pass * 256 + t;
    int o = item & 63, kp = item >> 6;
    int k = kp % 20, p = kp / 20;
    float y = 0.f;
#pragma unroll
    for (int c = 0; c < 6; ++c) y += w1p[o * 7 + c] * g[p][c][k];
    y = fmaxf(y * s1s[o] + b1s[o], 0.f);
    h1f[p][k][o] = y;
    h1b[p * 2048 + k * 64 + (((o >> 3) ^ (k & 7)) << 3) + (o & 7)] = f2b(y);
  }
  __syncthreads();

  {
    int p = w, o = lane;
    float mx = -INFINITY;
#pragma unroll
    for (int k = 0; k < 20; ++k) mx = fmaxf(mx, h1f[p][k][o]);
    float se = 0.f, sh = 0.f;
#pragma unroll
    for (int k = 0; k < 20; ++k) {
      float h = h1f[p][k][o];
      float e = __expf(h - mx);
      se += e; sh += h * e;
    }
    xcg[(size_t)(pbase + p) * 192 + o] = f2b(sh / se);
  }

  bf16x8 bfrag[2][2];
#pragma unroll
  for (int ks = 0; ks < 2; ++ks)
#pragma unroll
    for (int nt = 0; nt < 2; ++nt) {
      int kcol = nt * 16 + lr;
      int oc = ks * 4 + lg;
      bfrag[ks][nt] = *(const bf16x8*)&h1b[w * 2048 + kcol * 64 + ((oc ^ (kcol & 7)) << 3)];
    }
  f32x4 acc[8][2];
#pragma unroll
  for (int i = 0; i < 8; ++i) { acc[i][0] = (f32x4){0,0,0,0}; acc[i][1] = (f32x4){0,0,0,0}; }
#pragma unroll
  for (int i = 0; i < 8; ++i)
#pragma unroll
    for (int ks = 0; ks < 2; ++ks) {
      bf16x8 a = *(const bf16x8*)(w2b + (i * 16 + lr) * 64 + ks * 32 + lg * 8);
      acc[i][0] = __builtin_amdgcn_mfma_f32_16x16x32_bf16(a, bfrag[ks][0], acc[i][0], 0, 0, 0);
      acc[i][1] = __builtin_amdgcn_mfma_f32_16x16x32_bf16(a, bfrag[ks][1], acc[i][1], 0, 0, 0);
    }
  int pt = pbase + w;
#pragma unroll
  for (int i = 0; i < 8; ++i) {
    float x2o[4];
#pragma unroll
    for (int r = 0; r < 4; ++r) {
      int o = i * 16 + lg * 4 + r;
      float sv = s2[o], bv = b2[o];
      float v0 = fmaxf(acc[i][0][r] * sv + bv, 0.f);
      float v1 = fmaxf(acc[i][1][r] * sv + bv, 0.f);
      float vm = (lr < 4) ? fmaxf(v0, v1) : v0;
#pragma unroll
      for (int s = 1; s < 16; s <<= 1) vm = fmaxf(vm, __shfl_xor(vm, s));
      float e0 = __expf(v0 - vm);
      float e1 = (lr < 4) ? __expf(v1 - vm) : 0.f;
      float se = e0 + e1, sh = v0 * e0 + v1 * e1;
#pragma unroll
      for (int s = 1; s < 16; s <<= 1) { se += __shfl_xor(se, s); sh += __shfl_xor(sh, s); }
      x2o[r] = sh / se;
    }
    if (lr == 0) {
      ushort4 pk;
      pk.x = f2b(x2o[0]); pk.y = f2b(x2o[1]); pk.z = f2b(x2o[2]); pk.w = f2b(x2o[3]);
      *(ushort4*)&xcg[(size_t)pt * 192 + 64 + i * 16 + lg * 4] = pk;
    }
  }
}

// ---------------------------------------------------------------- GAC out-proj MFMA (merged)
__global__ __launch_bounds__(256, 2) void gacproj_kernel(
    const unsigned short* __restrict__ wob, const float* __restrict__ so,
    const float* __restrict__ bo, const unsigned short* __restrict__ xcg,
    unsigned short* __restrict__ Y0, unsigned short* __restrict__ Y1) {
  __shared__ __align__(16) unsigned short Al[128 * 64];
  __shared__ __align__(16) unsigned short Bl[128 * 64];
  int n0 = blockIdx.x * 128, o0 = blockIdx.y * 128;
  unsigned short* Yt = (n0 < BATCH * NP) ? Y0 : Y1;
  int nbase = n0 & (BATCH * NP - 1);
  int tid = threadIdx.x, w = tid >> 6, lane = tid & 63;
  int lr = lane & 15, lg = lane >> 4;
  int wa = w >> 1, wb = w & 1;
  f32x4 acc[4][4];
#pragma unroll
  for (int i = 0; i < 4; ++i)
#pragma unroll
    for (int j = 0; j < 4; ++j) acc[i][j] = (f32x4){0.f, 0.f, 0.f, 0.f};

  for (int k0 = 0; k0 < 192; k0 += 64) {
    __syncthreads();
#pragma unroll
    for (int u = 0; u < 4; ++u) {
      int C = u * 256 + tid;
      int row = C >> 3, j = C & 7;
      int js = j ^ (row & 7);
      gload_lds16(wob + (size_t)(o0 + row) * 192 + k0 + js * 8, Al + (u * 256 + w * 64) * 8);
      gload_lds16(xcg + (size_t)(n0 + row) * 192 + k0 + js * 8, Bl + (u * 256 + w * 64) * 8);
    }
    asm volatile("s_waitcnt vmcnt(0)" ::: "memory");
    __syncthreads();
#pragma unroll
    for (int kk = 0; kk < 2; ++kk) {
      bf16x8 af[4], bfr[4];
#pragma unroll
      for (int i = 0; i < 4; ++i) {
        int rowa = wa * 64 + i * 16 + lr;
        int ca = (kk * 4 + lg) ^ (rowa & 7);
        af[i] = *(const bf16x8*)(Al + rowa * 64 + ca * 8);
        int rowb = wb * 64 + i * 16 + lr;
        int cb = (kk * 4 + lg) ^ (rowb & 7);
        bfr[i] = *(const bf16x8*)(Bl + rowb * 64 + cb * 8);
      }
#pragma unroll
      for (int i = 0; i < 4; ++i)
#pragma unroll
        for (int j = 0; j < 4; ++j)
          acc[i][j] = __builtin_amdgcn_mfma_f32_16x16x32_bf16(af[i], bfr[j], acc[i][j], 0, 0, 0);
    }
  }
#pragma unroll
  for (int i = 0; i < 4; ++i) {
#pragma unroll
    for (int j = 0; j < 4; ++j) {
      int obase = o0 + wa * 64 + i * 16 + lg * 4;
      int n = nbase + wb * 64 + j * 16 + lr;
      ushort4 pk;
      pk.x = f2b(fmaxf(acc[i][j][0] * so[obase] + bo[obase], 0.f));
      pk.y = f2b(fmaxf(acc[i][j][1] * so[obase + 1] + bo[obase + 1], 0.f));
      pk.z = f2b(fmaxf(acc[i][j][2] * so[obase + 2] + bo[obase + 2], 0.f));
      pk.w = f2b(fmaxf(acc[i][j][3] * so[obase + 3] + bo[obase + 3], 0.f));
      *(ushort4*)&Yt[(size_t)n * DEMB + obase] = pk;
    }
  }
}

// ---------------------------------------------------------------- merged Q/K/V projection (6-in-1)
__global__ __launch_bounds__(256, 2) void qkv_kernel(
    const unsigned short* __restrict__ qw, const unsigned short* __restrict__ kw,
    const unsigned short* __restrict__ vw, const float* __restrict__ qbias,
    const float* __restrict__ kbias, const float* __restrict__ vbias,
    const unsigned short* __restrict__ d0t, const unsigned short* __restrict__ d1t,
    unsigned short* __restrict__ Q0, unsigned short* __restrict__ K0,
    unsigned short* __restrict__ V0, unsigned short* __restrict__ Q1,
    unsigned short* __restrict__ K1, unsigned short* __restrict__ V1) {
  __shared__ __align__(16) unsigned short Al[128 * 64];
  __shared__ __align__(16) unsigned short Bl[128 * 64];
  int z = blockIdx.z;
  int b = z & 3, which = z >> 2;
  int proj = which % 3, side = which / 3;
  const unsigned short* Wb = (proj == 0) ? qw : (proj == 1) ? kw : vw;
  const float* bias = (proj == 0) ? qbias : (proj == 1) ? kbias : vbias;
  const unsigned short* Bt = side ? d1t : d0t;
  unsigned short* Y = (which == 0) ? Q0 : (which == 1) ? K0 : (which == 2) ? V0
                    : (which == 3) ? Q1 : (which == 4) ? K1 : V1;
  float pscale = (proj == 0) ? 0.08838834764831845f : 1.f;
  int n0 = blockIdx.x * 128, o0 = blockIdx.y * 128;
  int tid = threadIdx.x, w = tid >> 6, lane = tid & 63;
  int lr = lane & 15, lg = lane >> 4;
  int wa = w >> 1, wb = w & 1;
  f32x4 acc[4][4];
#pragma unroll
  for (int i = 0; i < 4; ++i)
#pragma unroll
    for (int j = 0; j < 4; ++j) acc[i][j] = (f32x4){0.f, 0.f, 0.f, 0.f};

  for (int k0 = 0; k0 < DEMB; k0 += 64) {
    __syncthreads();
#pragma unroll
    for (int u = 0; u < 4; ++u) {
      int C = u * 256 + tid;
      int row = C >> 3, j = C & 7;
      int js = j ^ (row & 7);
      gload_lds16(Wb + (size_t)(o0 + row) * DEMB + k0 + js * 8, Al + (u * 256 + w * 64) * 8);
      gload_lds16(Bt + ((size_t)b * NP + n0 + row) * 512 + k0 + js * 8,
                  Bl + (u * 256 + w * 64) * 8);
    }
    asm volatile("s_waitcnt vmcnt(0)" ::: "memory");
    __syncthreads();
#pragma unroll
    for (int kk = 0; kk < 2; ++kk) {
      bf16x8 af[4], bfr[4];
#pragma unroll
      for (int i = 0; i < 4; ++i) {
        int rowa = wa * 64 + i * 16 + lr;
        int ca = (kk * 4 + lg) ^ (rowa & 7);
        af[i] = *(const bf16x8*)(Al + rowa * 64 + ca * 8);
        int rowb = wb * 64 + i * 16 + lr;
        int cb = (kk * 4 + lg) ^ (rowb & 7);
        bfr[i] = *(const bf16x8*)(Bl + rowb * 64 + cb * 8);
      }
#pragma unroll
      for (int i = 0; i < 4; ++i)
#pragma unroll
        for (int j = 0; j < 4; ++j)
          acc[i][j] = __builtin_amdgcn_mfma_f32_16x16x32_bf16(af[i], bfr[j], acc[i][j], 0, 0, 0);
    }
  }
#pragma unroll
  for (int i = 0; i < 4; ++i) {
#pragma unroll
    for (int j = 0; j < 4; ++j) {
#pragma unroll
      for (int r = 0; r < 4; ++r) {
        int o = o0 + wa * 64 + i * 16 + lg * 4 + r;
        int n = n0 + wb * 64 + j * 16 + lr;
        float v = (acc[i][j][r] + bias[o]) * pscale;
        int h = o & 3, dh = o >> 2;
        if (proj < 2) {
          Y[(((size_t)b * NH + h) * NP + n) * DHD + dh] = f2b(v);
        } else {
          Y[(((size_t)b * NH + h) * DHD + dh) * NP + n] = f2b(v);
        }
      }
    }
  }
}

// ---------------------------------------------------------------- MFMA projection GEMM, dual-side
template <int MODE, int KD>
__global__ __launch_bounds__(256, 2) void proj_mfma_kernel(
    const unsigned short* __restrict__ Wb, const float* __restrict__ bias,
    const unsigned short* __restrict__ Bt0, const unsigned short* __restrict__ Bt1,
    const unsigned short* __restrict__ Bt2_0, const unsigned short* __restrict__ Bt2_1,
    const unsigned short* __restrict__ D0, const unsigned short* __restrict__ D1,
    unsigned short* __restrict__ Y0, unsigned short* __restrict__ Y1) {
  __shared__ __align__(16) unsigned short Al[128 * 64];
  __shared__ __align__(16) unsigned short Bl[128 * 64];
  int z = blockIdx.z;
  int b = z & 3, side = z >> 2;
  const unsigned short* Bt = side ? Bt1 : Bt0;
  const unsigned short* Bt2 = side ? Bt2_1 : Bt2_0;
  const unsigned short* Dres = side ? D1 : D0;
  unsigned short* Y = side ? Y1 : Y0;
  int n0 = blockIdx.x * 128, o0 = blockIdx.y * 128;
  int tid = threadIdx.x, w = tid >> 6, lane = tid & 63;
  int lr = lane & 15, lg = lane >> 4;
  int wa = w >> 1, wb = w & 1;
  f32x4 acc[4][4];
#pragma unroll
  for (int i = 0; i < 4; ++i)
#pragma unroll
    for (int j = 0; j < 4; ++j) acc[i][j] = (f32x4){0.f, 0.f, 0.f, 0.f};

  for (int k0 = 0; k0 < KD; k0 += 64) {
    __syncthreads();
    const unsigned short* srcB; int kc;
    if (MODE == 4) { srcB = (k0 < 512) ? Bt : Bt2; kc = k0 & 511; }
    else { srcB = Bt; kc = k0; }
#pragma unroll
    for (int u = 0; u < 4; ++u) {
      int C = u * 256 + tid;
      int row = C >> 3, j = C & 7;
      int js = j ^ (row & 7);
      gload_lds16(Wb + (size_t)(o0 + row) * KD + k0 + js * 8, Al + (u * 256 + w * 64) * 8);
      gload_lds16(srcB + ((size_t)b * NP + n0 + row) * 512 + kc + js * 8,
                  Bl + (u * 256 + w * 64) * 8);
    }
    asm volatile("s_waitcnt vmcnt(0)" ::: "memory");
    __syncthreads();
#pragma unroll
    for (int kk = 0; kk < 2; ++kk) {
      bf16x8 af[4], bfr[4];
#pragma unroll
      for (int i = 0; i < 4; ++i) {
        int rowa = wa * 64 + i * 16 + lr;
        int ca = (kk * 4 + lg) ^ (rowa & 7);
        af[i] = *(const bf16x8*)(Al + rowa * 64 + ca * 8);
        int rowb = wb * 64 + i * 16 + lr;
        int cb = (kk * 4 + lg) ^ (rowb & 7);
        bfr[i] = *(const bf16x8*)(Bl + rowb * 64 + cb * 8);
      }
#pragma unroll
      for (int i = 0; i < 4; ++i)
#pragma unroll
        for (int j = 0; j < 4; ++j)
          acc[i][j] = __builtin_amdgcn_mfma_f32_16x16x32_bf16(af[i], bfr[j], acc[i][j], 0, 0, 0);
    }
  }
#pragma unroll
  for (int i = 0; i < 4; ++i) {
#pragma unroll
    for (int j = 0; j < 4; ++j) {
#pragma unroll
      for (int r = 0; r < 4; ++r) {
        int o = o0 + wa * 64 + i * 16 + lg * 4 + r;
        int n = n0 + wb * 64 + j * 16 + lr;
        float v = acc[i][j][r];
        if (MODE == 3) {
          v += bias[o];
        } else {
          v += b2f(Dres[((size_t)b * NP + n) * DEMB + o]);
        }
        Y[((size_t)b * NP + n) * DEMB + o] = f2b(v);
      }
    }
  }
}

// ---------------------------------------------------------------- MFMA flash attention (R13-proven)
__global__ __launch_bounds__(256, 2) void attn_mfma_kernel(
    const unsigned short* __restrict__ Q0, const unsigned short* __restrict__ K0,
    const unsigned short* __restrict__ V0, const unsigned short* __restrict__ Q1,
    const unsigned short* __restrict__ K1, const unsigned short* __restrict__ V1,
    unsigned short* __restrict__ att0, unsigned short* __restrict__ att1) {
  __shared__ __align__(16) unsigned short Klds[2][8192];
  __shared__ __align__(16) unsigned short Vlds[2][8192];
  __shared__ __align__(16) float Pws[4][544];

  int hw = blockIdx.x;                       // grid = 512, 512 % 8 == 0
  int lid = ((hw & 7) << 6) + (hw >> 3);     // bijective XCD swizzle
  int which = lid >> 8;
  int blk = lid & 255;
  const unsigned short* Qb = which ? Q1 : Q0;
  const unsigned short* Kb = which ? K0 : K1;
  const unsigned short* Vb = which ? V0 : V1;
  unsigned short* att = which ? att1 : att0;

  int bh = blk >> 4, qt = blk & 15;
  int tid = threadIdx.x;
  int w = tid >> 6, lane = tid & 63;
  int lr = lane & 15, lg = lane >> 4;
  int q0 = qt * 128 + w * 32;

  bf16x8 qf[2][4];
#pragma unroll
  for (int f = 0; f < 2; ++f) {
    const unsigned short* Qrow = Qb + ((size_t)bh * NP + q0 + f * 16 + lr) * DHD + lg * 8;
#pragma unroll
    for (int ds = 0; ds < 4; ++ds) qf[f][ds] = *(const bf16x8*)(Qrow + ds * 32);
  }

  const unsigned short* Kg = Kb + (size_t)bh * NP * DHD;
  const unsigned short* Vg = Vb + (size_t)bh * DHD * NP;
  unsigned short* Pl = (unsigned short*)&Pws[w][0];

  f32x4 o[2][8];
#pragma unroll
  for (int f = 0; f < 2; ++f)
#pragma unroll
    for (int ds = 0; ds < 8; ++ds) o[f][ds] = (f32x4){0.f, 0.f, 0.f, 0.f};
  float mrun[2][4], lrun[2][4];
#pragma unroll
  for (int f = 0; f < 2; ++f)
#pragma unroll
    for (int r = 0; r < 4; ++r) { mrun[f][r] = -INFINITY; lrun[f][r] = 0.f; }

  // prologue: stage tile 0 into buffer 0
#pragma unroll
  for (int u = 0; u < 4; ++u) {
    int C = (w * 4 + u) * 64 + lane;
    int key = C >> 4, jl = C & 15, j = jl ^ (key & 15);
    gload_lds16(Kg + (size_t)key * DHD + j * 8, &Klds[0][(w * 4 + u) * 512]);
    int d = C >> 3, jv = (C & 7) ^ (d & 7);
    gload_lds16(Vg + (size_t)d * NP + jv * 8, &Vlds[0][(w * 4 + u) * 512]);
  }
  asm volatile("s_waitcnt vmcnt(0)" ::: "memory");
  __syncthreads();

  for (int tIdx = 0; tIdx < 32; ++tIdx) {
    int cur = tIdx & 1;
    // stage next tile into the other buffer (async, no wait)
    if (tIdx < 31) {
      int kv0 = (tIdx + 1) * 64;
#pragma unroll
      for (int u = 0; u < 4; ++u) {
        int C = (w * 4 + u) * 64 + lane;
        int key = C >> 4, jl = C & 15, j = jl ^ (key & 15);
        gload_lds16(Kg + (size_t)(kv0 + key) * DHD + j * 8, &Klds[cur ^ 1][(w * 4 + u) * 512]);
        int d = C >> 3, jv = (C & 7) ^ (d & 7);
        gload_lds16(Vg + (size_t)d * NP + kv0 + jv * 8, &Vlds[cur ^ 1][(w * 4 + u) * 512]);
      }
    }
    // QK^T for both fragments (K-fragments loaded once, shared)
    __builtin_amdgcn_s_setprio(1);
    f32x4 s[2][4];
#pragma unroll
    for (int ks = 0; ks < 4; ++ks) {
      s[0][ks] = (f32x4){0.f, 0.f, 0.f, 0.f};
      s[1][ks] = (f32x4){0.f, 0.f, 0.f, 0.f};
      int key = ks * 16 + lr;
#pragma unroll
      for (int dstep = 0; dstep < 4; ++dstep) {
        int dbyte = (lg * 16 + dstep * 64) ^ ((key & 15) << 4);
        bf16x8 kb = *(const bf16x8*)(&Klds[cur][0] + key * 128 + (dbyte >> 1));
        s[0][ks] = __builtin_amdgcn_mfma_f32_16x16x32_bf16(qf[0][dstep], kb, s[0][ks], 0, 0, 0);
        s[1][ks] = __builtin_amdgcn_mfma_f32_16x16x32_bf16(qf[1][dstep], kb, s[1][ks], 0, 0, 0);
      }
    }
    __builtin_amdgcn_s_setprio(0);
    // online softmax with defer-max (both fragments); max reduce only
    float tmax[2][4];
#pragma unroll
    for (int f = 0; f < 2; ++f)
#pragma unroll
      for (int r = 0; r < 4; ++r) {
        float m = fmaxf(fmaxf(s[f][0][r], s[f][1][r]), fmaxf(s[f][2][r], s[f][3][r]));
#pragma unroll
        for (int msk = 1; msk < 16; msk <<= 1) m = fmaxf(m, __shfl_xor(m, msk));
        tmax[f][r] = m;
      }
    int need = 0;
#pragma unroll
    for (int f = 0; f < 2; ++f)
#pragma unroll
      for (int r = 0; r < 4; ++r) need |= (tmax[f][r] > mrun[f][r]) ? 1 : 0;
    float fac[2][4];
#pragma unroll
    for (int f = 0; f < 2; ++f)
#pragma unroll
      for (int r = 0; r < 4; ++r) fac[f][r] = 1.f;
    if (__any(need)) {
#pragma unroll
      for (int f = 0; f < 2; ++f)
#pragma unroll
        for (int r = 0; r < 4; ++r) {
          float mnew = fmaxf(mrun[f][r], tmax[f][r]);
          fac[f][r] = __expf(mrun[f][r] - mnew);
          mrun[f][r] = mnew;
        }
#pragma unroll
      for (int f = 0; f < 2; ++f)
#pragma unroll
        for (int ds = 0; ds < 8; ++ds)
#pragma unroll
          for (int r = 0; r < 4; ++r) o[f][ds][r] *= fac[f][r];
    }
    // per-fragment: P write + per-lane partial sum + PV
#pragma unroll
    for (int f = 0; f < 2; ++f) {
      float ps[4] = {0.f, 0.f, 0.f, 0.f};
#pragma unroll
      for (int ks = 0; ks < 4; ++ks) {
        int k = ks * 16 + lr;
#pragma unroll
        for (int r = 0; r < 4; ++r) {
          float p = __expf(s[f][ks][r] - mrun[f][r]);
          ps[r] += p;
          int q = lg * 4 + r;
          int kbyte = (k * 2) ^ ((q & 7) << 4);
          Pl[q * 64 + (kbyte >> 1)] = f2b(p);
        }
      }
#pragma unroll
      for (int r = 0; r < 4; ++r)
        lrun[f][r] = lrun[f][r] * fac[f][r] + ps[r];
      __builtin_amdgcn_s_setprio(1);
#pragma unroll
      for (int ks2 = 0; ks2 < 2; ++ks2) {
        int kbyte = ((lg * 8 + ks2 * 32) * 2) ^ ((lr & 7) << 4);
        bf16x8 pa = *(const bf16x8*)(Pl + lr * 64 + (kbyte >> 1));
#pragma unroll
        for (int ds = 0; ds < 8; ++ds) {
          int d = ds * 16 + lr;
          int keybyte = ((lg * 8 + ks2 * 32) * 2) ^ ((d & 7) << 4);
          bf16x8 vb = *(const bf16x8*)(&Vlds[cur][0] + d * 64 + (keybyte >> 1));
          o[f][ds] = __builtin_amdgcn_mfma_f32_16x16x32_bf16(pa, vb, o[f][ds], 0, 0, 0);
        }
      }
      __builtin_amdgcn_s_setprio(0);
    }
    asm volatile("s_waitcnt vmcnt(0)" ::: "memory");
    __syncthreads();
  }

  // final sum reduce (once, not per tile)
#pragma unroll
  for (int f = 0; f < 2; ++f)
#pragma unroll
    for (int r = 0; r < 4; ++r) {
      float s = lrun[f][r];
#pragma unroll
      for (int msk = 1; msk < 16; msk <<= 1) s += __shfl_xor(s, msk);
      lrun[f][r] = s;
    }

  int b = bh >> 2, h = bh & 3;
  float* ost = &Pws[w][0];
#pragma unroll
  for (int f = 0; f < 2; ++f) {
    float linv[4];
#pragma unroll
    for (int r = 0; r < 4; ++r) linv[r] = 1.f / lrun[f][r];
    unsigned short* outb = att + ((size_t)b * NP + q0 + f * 16) * DEMB;
#pragma unroll
    for (int c = 0; c < 4; ++c) {
#pragma unroll
      for (int half = 0; half < 2; ++half) {
        int ds = 2 * c + half;
#pragma unroll
        for (int r = 0; r < 4; ++r)
          ost[(lg * 4 + r) * 33 + half * 16 + lr] = o[f][ds][r] * linv[r];
      }
#pragma unroll
      for (int it = 0; it < 8; ++it) {
        int q = lr, dl = it * 4 + lg;
        int d = c * 32 + dl;
        outb[(size_t)q * DEMB + d * 4 + h] = f2b(ost[q * 33 + dl]);
      }
    }
  }
}

// ---------------------------------------------------------------- dists: bf16 MFMA GEMM -> bf16 S (B,NP,NP)
__global__ __launch_bounds__(256, 2) void dists_mfma_kernel(
    const unsigned short* __restrict__ At, const unsigned short* __restrict__ Bt,
    unsigned short* __restrict__ S) {
  __shared__ __align__(16) unsigned short Sh[2][8192];
  int b = blockIdx.z;
  int n0 = blockIdx.y * 128, m0 = blockIdx.x * 128;
  int tid = threadIdx.x, w = tid >> 6, lane = tid & 63;
  int lr = lane & 15, lg = lane >> 4;
  int wn = w >> 1, wm = w & 1;
  const unsigned short* Ab = At + ((size_t)b * NP + n0) * DEMB;
  const unsigned short* Bb = Bt + ((size_t)b * NP + m0) * DEMB;
  f32x4 acc[4][4];
#pragma unroll
  for (int i = 0; i < 4; ++i)
#pragma unroll
    for (int j = 0; j < 4; ++j) acc[i][j] = (f32x4){0.f, 0.f, 0.f, 0.f};

  for (int k0 = 0; k0 < DEMB; k0 += 64) {
    __syncthreads();
#pragma unroll
    for (int u = 0; u < 4; ++u) {
      int C = u * 256 + tid;
      int row = C >> 3, j = C & 7;
      int js = j ^ (row & 7);
      gload_lds16(Ab + (size_t)row * DEMB + k0 + js * 8, &Sh[0][(u * 256 + w * 64) * 8]);
      gload_lds16(Bb + (size_t)row * DEMB + k0 + js * 8, &Sh[1][(u * 256 + w * 64) * 8]);
    }
    asm volatile("s_waitcnt vmcnt(0)" ::: "memory");
    __syncthreads();
#pragma unroll
    for (int kk = 0; kk < 2; ++kk) {
      bf16x8 af[4], bfr[4];
#pragma unroll
      for (int i = 0; i < 4; ++i) {
        int rowa = wn * 64 + i * 16 + lr;
        int ca = (kk * 4 + lg) ^ (rowa & 7);
        af[i] = *(const bf16x8*)(&Sh[0][0] + rowa * 64 + ca * 8);
        int rowb = wm * 64 + i * 16 + lr;
        int cb = (kk * 4 + lg) ^ (rowb & 7);
        bfr[i] = *(const bf16x8*)(&Sh[1][0] + rowb * 64 + cb * 8);
      }
#pragma unroll
      for (int i = 0; i < 4; ++i)
#pragma unroll
        for (int j = 0; j < 4; ++j)
          acc[i][j] = __builtin_amdgcn_mfma_f32_16x16x32_bf16(af[i], bfr[j], acc[i][j], 0, 0, 0);
    }
  }
  const float scale = 0.04419417382415922f;
  __syncthreads();
  unsigned short* Cs = &Sh[0][0];
#pragma unroll
  for (int i = 0; i < 4; ++i)
#pragma unroll
    for (int j = 0; j < 4; ++j)
#pragma unroll
      for (int r = 0; r < 4; ++r) {
        int nl = wn * 64 + i * 16 + lg * 4 + r;
        int ml = wm * 64 + j * 16 + lr;
        Cs[nl * 128 + ml] = f2b(acc[i][j][r] * scale);
      }
  __syncthreads();
  unsigned short* Sb = S + (size_t)b * NP * NP;
#pragma unroll
  for (int it = 0; it < 8; ++it) {
    int chunk = it * 256 + tid;
    int rowl = chunk >> 4, c8 = (chunk & 15) * 8;
    *(bf16x8*)(Sb + (size_t)(n0 + rowl) * NP + m0 + c8) = *(const bf16x8*)(Cs + rowl * 128 + c8);
  }
}

// ---------------------------------------------------------------- sinkhorn via potentials (bf16 S)
__global__ __launch_bounds__(256) void sink_u_kernel(const unsigned short* __restrict__ S,
                                                     const float* __restrict__ v,
                                                     float* __restrict__ u) {
  int t = threadIdx.x, w = t >> 6, lane = t & 63;
  int rowid = blockIdx.x * 4 + w;
  int b = rowid >> 11, i = rowid & 2047;
  const unsigned short* row = S + ((size_t)b * NP + i) * NP;
  const float* vb = v + (size_t)b * NP;
  float m = -INFINITY, s = 0.f;
#pragma unroll
  for (int c = 0; c < 4; ++c) {
    int off = c * 512 + lane * 8;
    bf16x8 x8 = *(const bf16x8*)(row + off);
    float4 va = *(const float4*)(vb + off);
    float4 vc = *(const float4*)(vb + off + 4);
    float xs[8];
    xs[0] = b2f(x8[0]) + va.x; xs[1] = b2f(x8[1]) + va.y;
    xs[2] = b2f(x8[2]) + va.z; xs[3] = b2f(x8[3]) + va.w;
    xs[4] = b2f(x8[4]) + vc.x; xs[5] = b2f(x8[5]) + vc.y;
    xs[6] = b2f(x8[6]) + vc.z; xs[7] = b2f(x8[7]) + vc.w;
    float mc = fmaxf(fmaxf(fmaxf(xs[0], xs[1]), fmaxf(xs[2], xs[3])),
                     fmaxf(fmaxf(xs[4], xs[5]), fmaxf(xs[6], xs[7])));
    float sc = 0.f;
#pragma unroll
    for (int e = 0; e < 8; ++e) sc += __expf(xs[e] - mc);
    float M = fmaxf(m, mc);
    s = s * __expf(m - M) + sc * __expf(mc - M);
    m = M;
  }
#pragma unroll
  for (int st = 1; st < 64; st <<= 1) {
    float m2 = __shfl_xor(m, st), s2 = __shfl_xor(s, st);
    float M = fmaxf(m, m2);
    s = s * __expf(m - M) + s2 * __expf(m2 - M);
    m = M;
  }
  if (lane == 0) {
    float M = fmaxf(m, 0.f);
    float ss = s * __expf(m - M) + __expf(-M);
    u[(size_t)b * NP + i] = -(M + logf(ss));
  }
}

// column partials + fused final reduce (last-block pattern): writes v directly
__global__ void sink_c1_kernel(const unsigned short* __restrict__ S, const float* __restrict__ u,
                               float* __restrict__ colM, float* __restrict__ colS,
                               float* __restrict__ v, int* __restrict__ cnt) {
  int ctile = blockIdx.x, part = blockIdx.y, b = blockIdx.z;
  int t = threadIdx.x, ry = t >> 6, cx = t & 63;
  int c0 = ctile * 128 + cx * 2;
  int rbase = part * 256 + ry * 64;
  const unsigned short* Sb = S + (size_t)b * NP * NP;
  const float* ub = u + (size_t)b * NP;
  float m0 = -INFINITY, s0 = 0.f, m1 = -INFINITY, s1 = 0.f;
  for (int r8 = 0; r8 < 64; r8 += 8) {
    float x0[8], x1[8];
#pragma unroll
    for (int k = 0; k < 8; ++k) {
      int r = rbase + r8 + k;
      unsigned pk = *(const unsigned*)(Sb + (size_t)r * NP + c0);
      float uu = ub[r];
      x0[k] = b2f((unsigned short)pk) + uu;
      x1[k] = b2f((unsigned short)(pk >> 16)) + uu;
    }
    float mc0 = x0[0], mc1 = x1[0];
#pragma unroll
    for (int k = 1; k < 8; ++k) { mc0 = fmaxf(mc0, x0[k]); mc1 = fmaxf(mc1, x1[k]); }
    float sc0 = 0.f, sc1 = 0.f;
#pragma unroll
    for (int k = 0; k < 8; ++k) { sc0 += __expf(x0[k] - mc0); sc1 += __expf(x1[k] - mc1); }
    float M0 = fmaxf(m0, mc0);
    s0 = s0 * __expf(m0 - M0) + sc0 * __expf(mc0 - M0); m0 = M0;
    float M1 = fmaxf(m1, mc1);
    s1 = s1 * __expf(m1 - M1) + sc1 * __expf(mc1 - M1); m1 = M1;
  }
  __shared__ float pm[4][128], ps[4][128];
  __shared__ int islast;
  pm[ry][cx * 2] = m0; pm[ry][cx * 2 + 1] = m1;
  ps[ry][cx * 2] = s0; ps[ry][cx * 2 + 1] = s1;
  __syncthreads();
  if (t < 128) {
    float m = pm[0][t], s = ps[0][t];
    for (int k = 1; k < 4; ++k) {
      float m2 = pm[k][t], s2 = ps[k][t];
      float M = fmaxf(m, m2);
      s = s * __expf(m - M) + s2 * __expf(m2 - M);
      m = M;
    }
    size_t oo = ((size_t)b * NP + ctile * 128 + t) * 8 + part;
    colM[oo] = m; colS[oo] = s;
  }
  // last-block-done: release stores, count, acquire, final reduce (was sink_c2)
  __threadfence();
  if (t == 0) islast = (atomicAdd(cnt, 1) == 511) ? 1 : 0;
  __syncthreads();
  if (islast) {
    __threadfence();
    for (int i = t; i < BATCH * NP; i += 256) {
      float m = -INFINITY, s = 0.f;
      for (int p = 0; p < 8; ++p) {
        float m2 = colM[(size_t)i * 8 + p], s2 = colS[(size_t)i * 8 + p];
        float M = fmaxf(m, m2);
        s = s * __expf(m - M) + s2 * __expf(m2 - M);
        m = M;
      }
      float M = fmaxf(m, 0.f);
      s = s * __expf(m - M) + __expf(-M);
      v[i] = -(M + logf(s));
    }
  }
}

// ---------------------------------------------------------------- perm: wave-per-row, no barriers
__global__ __launch_bounds__(256) void perm_kernel(
    const unsigned short* __restrict__ S, const float* __restrict__ u,
    const float* __restrict__ v, const float* __restrict__ tgt,
    float* __restrict__ outp, float* __restrict__ weights, float* __restrict__ wt) {
  int t = threadIdx.x, w = t >> 6, lane = t & 63;
  int rowid = blockIdx.x * 4 + w;
  int b = rowid >> 11, n = rowid & 2047;
  const unsigned short* row = S + ((size_t)b * NP + n) * NP;
  const float* vb = v + (size_t)b * NP;
  float ui = u[(size_t)b * NP + n];
  float ev[32];
  float lsum = 0.f, lm = -INFINITY;
#pragma unroll
  for (int c = 0; c < 4; ++c) {
    int off = c * 512 + lane * 8;
    bf16x8 x8 = *(const bf16x8*)(row + off);
    float4 va = *(const float4*)(vb + off);
    float4 vc = *(const float4*)(vb + off + 4);
    float e0 = __expf(b2f(x8[0]) + ui + va.x);
    float e1 = __expf(b2f(x8[1]) + ui + va.y);
    float e2 = __expf(b2f(x8[2]) + ui + va.z);
    float e3 = __expf(b2f(x8[3]) + ui + va.w);
    float e4 = __expf(b2f(x8[4]) + ui + vc.x);
    float e5 = __expf(b2f(x8[5]) + ui + vc.y);
    float e6 = __expf(b2f(x8[6]) + ui + vc.z);
    float e7 = __expf(b2f(x8[7]) + ui + vc.w);
    ev[c * 8 + 0] = e0; ev[c * 8 + 1] = e1; ev[c * 8 + 2] = e2; ev[c * 8 + 3] = e3;
    ev[c * 8 + 4] = e4; ev[c * 8 + 5] = e5; ev[c * 8 + 6] = e6; ev[c * 8 + 7] = e7;
    lsum += e0 + e1 + e2 + e3 + e4 + e5 + e6 + e7;
    lm = fmaxf(lm, fmaxf(fmaxf(fmaxf(e0, e1), fmaxf(e2, e3)),
                          fmaxf(fmaxf(e4, e5), fmaxf(e6, e7))));
  }
#pragma unroll
  for (int st = 1; st < 64; st <<= 1) {
    lsum += __shfl_xor(lsum, st);
    lm = fmaxf(lm, __shfl_xor(lm, st));
  }
  float inv = 1.f / (lsum + 1e-8f);
  // write pn + accumulate weighted-tgt partials
  const float* tb = tgt + (size_t)b * 3 * NP;
  float* op = outp + ((size_t)b * NP + n) * NP;
  float av0 = 0.f, av1 = 0.f, av2 = 0.f;
#pragma unroll
  for (int c = 0; c < 4; ++c) {
    int off = c * 512 + lane * 8;
    float p0 = ev[c * 8 + 0] * inv, p1 = ev[c * 8 + 1] * inv;
    float p2 = ev[c * 8 + 2] * inv, p3 = ev[c * 8 + 3] * inv;
    float p4 = ev[c * 8 + 4] * inv, p5 = ev[c * 8 + 5] * inv;
    float p6 = ev[c * 8 + 6] * inv, p7 = ev[c * 8 + 7] * inv;
    float4 o0 = {p0, p1, p2, p3};
    float4 o1 = {p4, p5, p6, p7};
    *(float4*)(op + off) = o0;
    *(float4*)(op + off + 4) = o1;
    float4 t0a = *(const float4*)(tb + off);
    float4 t0b = *(const float4*)(tb + off + 4);
    av0 += p0 * t0a.x + p1 * t0a.y + p2 * t0a.z + p3 * t0a.w +
           p4 * t0b.x + p5 * t0b.y + p6 * t0b.z + p7 * t0b.w;
    float4 t1a = *(const float4*)(tb + NP + off);
    float4 t1b = *(const float4*)(tb + NP + off + 4);
    av1 += p0 * t1a.x + p1 * t1a.y + p2 * t1a.z + p3 * t1a.w +
           p4 * t1b.x + p5 * t1b.y + p6 * t1b.z + p7 * t1b.w;
    float4 t2a = *(const float4*)(tb + 2 * NP + off);
    float4 t2b = *(const float4*)(tb + 2 * NP + off + 4);
    av2 += p0 * t2a.x + p1 * t2a.y + p2 * t2a.z + p3 * t2a.w +
           p4 * t2b.x + p5 * t2b.y + p6 * t2b.z + p7 * t2b.w;
  }
#pragma unroll
  for (int st = 1; st < 64; st <<= 1) {
    av0 += __shfl_xor(av0, st);
    av1 += __shfl_xor(av1, st);
    av2 += __shfl_xor(av2, st);
  }
  if (lane == 0) {
    wt[((size_t)b * 3 + 0) * NP + n] = av0;
    wt[((size_t)b * 3 + 1) * NP + n] = av1;
    wt[((size_t)b * 3 + 2) * NP + n] = av2;
    weights[(size_t)b * NP + n] = lm;
  }
}

// ---------------------------------------------------------------- 3x3 Kabsch helpers (fp64)
__device__ double det3d(const double M[3][3]) {
  return M[0][0] * (M[1][1] * M[2][2] - M[1][2] * M[2][1])
       - M[0][1] * (M[1][0] * M[2][2] - M[1][2] * M[2][0])
       + M[0][2] * (M[1][0] * M[2][1] - M[1][1] * M[2][0]);
}

#define JROT(p, q)                                                              \
  do {                                                                          \
    double apq = S[p][q];                                                       \
    if (fabs(apq) > 1e-60) {                                                    \
      double tau = (S[q][q] - S[p][p]) / (2.0 * apq);                           \
      double tt = (tau >= 0.0) ? 1.0 / (tau + sqrt(1.0 + tau * tau))            \
                               : 1.0 / (tau - sqrt(1.0 + tau * tau));           \
      double cr = 1.0 / sqrt(1.0 + tt * tt), sr = tt * cr;                      \
      _Pragma("unroll") for (int k = 0; k < 3; ++k) {                           \
        double skp = S[k][p], skq = S[k][q];                                    \
        S[k][p] = cr * skp - sr * skq;  S[k][q] = sr * skp + cr * skq;          \
      }                                                                         \
      _Pragma("unroll") for (int k = 0; k < 3; ++k) {                           \
        double spk = S[p][k], sqk = S[q][k];                                    \
        S[p][k] = cr * spk - sr * sqk;  S[q][k] = sr * spk + cr * sqk;          \
      }                                                                         \
      _Pragma("unroll") for (int k = 0; k < 3; ++k) {                           \
        double vkp = V[k][p], vkq = V[k][q];                                    \
        V[k][p] = cr * vkp - sr * vkq;  V[k][q] = sr * vkp + cr * vkq;          \
      }                                                                         \
    }                                                                           \
  } while (0)

#define CSWAPCOL(i, j, ei, ej)                                                  \
  if (ei < ej) {                                                                \
    double tt_ = ei; ei = ej; ej = tt_;                                         \
    _Pragma("unroll") for (int r = 0; r < 3; ++r) {                             \
      double tv = V[r][i]; V[r][i] = V[r][j]; V[r][j] = tv;                     \
    }                                                                           \
  }

// ---------------------------------------------------------------- cent+Hm+Kabsch fused (1 block per batch)
__global__ __launch_bounds__(256) void cent_hm_solve_kernel(
    const float* __restrict__ src, const float* __restrict__ wt,
    const float* __restrict__ weights, float* __restrict__ out) {
  int b = blockIdx.x, t = threadIdx.x;
  int w = t >> 6, lane = t & 63;
  __shared__ float xr[4][16];
  const float* sb = src + (size_t)b * 3 * NP;
  const float* wb = wt + (size_t)b * 3 * NP;
  const float* ww = weights + (size_t)b * NP;
  float lw[8], ls0[8], ls1[8], ls2[8], lt0[8], lt1[8], lt2[8];
#pragma unroll
  for (int i = 0; i < 8; ++i) {
    int n = t + i * 256;
    lw[i] = ww[n];
    ls0[i] = sb[n]; ls1[i] = sb[NP + n]; ls2[i] = sb[2 * NP + n];
    lt0[i] = wb[n]; lt1[i] = wb[NP + n]; lt2[i] = wb[2 * NP + n];
  }
  // phase 1: wsum
  float s = 0.f;
#pragma unroll
  for (int i = 0; i < 8; ++i) s += lw[i];
#pragma unroll
  for (int st = 1; st < 64; st <<= 1) s += __shfl_xor(s, st);
  if (lane == 0) xr[w][0] = s;
  __syncthreads();
  float wsum = xr[0][0] + xr[1][0] + xr[2][0] + xr[3][0];
  float inv = 1.f / (wsum + 1e-8f);
  // phase 2: 6 weighted centroids
  float a[6] = {};
#pragma unroll
  for (int i = 0; i < 8; ++i) {
    float wv = lw[i] * inv;
    a[0] += ls0[i] * wv; a[1] += ls1[i] * wv; a[2] += ls2[i] * wv;
    a[3] += lt0[i] * wv; a[4] += lt1[i] * wv; a[5] += lt2[i] * wv;
  }
#pragma unroll
  for (int k = 0; k < 6; ++k)
#pragma unroll
    for (int st = 1; st < 64; st <<= 1) a[k] += __shfl_xor(a[k], st);
  __syncthreads();
  if (lane == 0) {
#pragma unroll
    for (int k = 0; k < 6; ++k) xr[w][k] = a[k];
  }
  __syncthreads();
  float cc[6];
#pragma unroll
  for (int k = 0; k < 6; ++k) cc[k] = xr[0][k] + xr[1][k] + xr[2][k] + xr[3][k];
  // phase 3: 9 covariance entries
  float h[9] = {};
#pragma unroll
  for (int i = 0; i < 8; ++i) {
    float wv = lw[i] * inv;
    float s0 = ls0[i] - cc[0], s1 = ls1[i] - cc[1], s2 = ls2[i] - cc[2];
    float d0 = (lt0[i] - cc[3]) * wv, d1 = (lt1[i] - cc[4]) * wv, d2 = (lt2[i] - cc[5]) * wv;
    h[0] += s0 * d0; h[1] += s0 * d1; h[2] += s0 * d2;
    h[3] += s1 * d0; h[4] += s1 * d1; h[5] += s1 * d2;
    h[6] += s2 * d0; h[7] += s2 * d1; h[8] += s2 * d2;
  }
#pragma unroll
  for (int k = 0; k < 9; ++k)
#pragma unroll
    for (int st = 1; st < 64; st <<= 1) h[k] += __shfl_xor(h[k], st);
  __syncthreads();
  if (lane == 0) {
#pragma unroll
    for (int k = 0; k < 9; ++k) xr[w][k] = h[k];
  }
  __syncthreads();
  if (t == 0) {
    float hm9[9];
#pragma unroll
    for (int k = 0; k < 9; ++k) hm9[k] = xr[0][k] + xr[1][k] + xr[2][k] + xr[3][k];
    double A[3][3];
#pragma unroll
    for (int r = 0; r < 3; ++r)
#pragma unroll
      for (int c = 0; c < 3; ++c) A[r][c] = (double)hm9[r * 3 + c];
    double S[3][3];
#pragma unroll
    for (int i = 0; i < 3; ++i)
#pragma unroll
      for (int j = 0; j < 3; ++j) {
        double acc = 0.0;
#pragma unroll
        for (int k = 0; k < 3; ++k) acc += A[k][i] * A[k][j];
        S[i][j] = acc;
      }
    double V[3][3] = {{1, 0, 0}, {0, 1, 0}, {0, 0, 1}};
    for (int sweep = 0; sweep < 12; ++sweep) {
      JROT(0, 1); JROT(0, 2); JROT(1, 2);
    }
    double e0 = S[0][0], e1 = S[1][1], e2 = S[2][2];
    CSWAPCOL(0, 1, e0, e1);
    CSWAPCOL(0, 2, e0, e2);
    CSWAPCOL(1, 2, e1, e2);
    double Us[3][3];
#pragma unroll
    for (int i = 0; i < 3; ++i) {
      double v0 = V[0][i], v1 = V[1][i], v2 = V[2][i];
      double u0 = A[0][0] * v0 + A[0][1] * v1 + A[0][2] * v2;
      double u1 = A[1][0] * v0 + A[1][1] * v1 + A[1][2] * v2;
      double u2 = A[2][0] * v0 + A[2][1] * v1 + A[2][2] * v2;
      double nrm = sqrt(u0 * u0 + u1 * u1 + u2 * u2);
      if (nrm > 1e-30) { u0 /= nrm; u1 /= nrm; u2 /= nrm; }
      else if (i == 2) {
        u0 = Us[1][0] * Us[2][1] - Us[2][0] * Us[1][1];
        u1 = Us[2][0] * Us[0][1] - Us[0][0] * Us[2][1];
        u2 = Us[0][0] * Us[1][1] - Us[1][0] * Us[0][1];
        double nn = sqrt(u0 * u0 + u1 * u1 + u2 * u2);
        if (nn > 1e-30) { u0 /= nn; u1 /= nn; u2 /= nn; }
      }
      Us[0][i] = u0; Us[1][i] = u1; Us[2][i] = u2;
    }
    double d = det3d(V) * det3d(Us);
    double R[3][3];
#pragma unroll
    for (int i = 0; i < 3; ++i)
#pragma unroll
      for (int j = 0; j < 3; ++j)
        R[i][j] = V[i][0] * Us[j][0] + V[i][1] * Us[j][1] + d * V[i][2] * Us[j][2];
    double sc[3] = {(double)cc[0], (double)cc[1], (double)cc[2]};
    double tc[3] = {(double)cc[3], (double)cc[4], (double)cc[5]};
#pragma unroll
    for (int r = 0; r < 3; ++r)
#pragma unroll
      for (int c = 0; c < 3; ++c) out[b * 9 + r * 3 + c] = (float)R[r][c];
#pragma unroll
    for (int i = 0; i < 3; ++i) {
      double tv = tc[i] - (R[i][0] * sc[0] + R[i][1] * sc[1] + R[i][2] * sc[2]);
      out[36 + b * 3 + i] = (float)tv;
    }
  }
}

// ---------------------------------------------------------------- launch
extern "C" void kernel_launch(void* const* d_in, const int* in_sizes, int n_in,
                              void* d_out, int out_size, void* d_ws, size_t ws_size,
                              hipStream_t stream) {
  const float* src  = (const float*)d_in[0];
  const float* tgt  = (const float*)d_in[1];
  const float* g_w1 = (const float*)d_in[2];
  const float* g_s1 = (const float*)d_in[3];
  const float* g_b1 = (const float*)d_in[4];
  const float* g_w2 = (const float*)d_in[5];
  const float* g_s2 = (const float*)d_in[6];
  const float* g_b2 = (const float*)d_in[7];
  const float* g_wo = (const float*)d_in[8];
  const float* g_so = (const float*)d_in[9];
  const float* g_bo = (const float*)d_in[10];
  const float* q_w  = (const float*)d_in[11];
  const float* q_b  = (const float*)d_in[12];
  const float* k_w  = (const float*)d_in[13];
  const float* k_b  = (const float*)d_in[14];
  const float* v_w  = (const float*)d_in[15];
  const float* v_b  = (const float*)d_in[16];
  const float* m_w  = (const float*)d_in[17];
  const float* m_b  = (const float*)d_in[18];
  const float* mlp_w = (const float*)d_in[19];
  float* out = (float*)d_out;
  float* ws = (float*)d_ws;

  const size_t SLOT = 4194304;  // 16 MB slots (in floats)
  unsigned short* d0t  = (unsigned short*)(ws + 0 * SLOT);
  unsigned short* d1t  = (unsigned short*)(ws + 1 * SLOT);
  unsigned short* Q0   = (unsigned short*)(ws + 2 * SLOT);
  unsigned short* K0   = (unsigned short*)(ws + 3 * SLOT);
  unsigned short* V0   = (unsigned short*)(ws + 4 * SLOT);
  unsigned short* Q1   = (unsigned short*)(ws + 5 * SLOT);
  unsigned short* K1   = (unsigned short*)(ws + 6 * SLOT);
  unsigned short* V1   = (unsigned short*)(ws + 7 * SLOT);
  unsigned short* att0t = (unsigned short*)(ws + 8 * SLOT);
  unsigned short* att1t = (unsigned short*)(ws + 9 * SLOT);
  unsigned short* mp0t = Q0;
  unsigned short* mp1t = Q1;
  unsigned short* d0nt = att0t;
  unsigned short* d1nt = att1t;
  unsigned short* base3  = (unsigned short*)(ws + 3 * SLOT);
  unsigned short* q_wb   = base3 + 4456448;
  unsigned short* k_wb   = q_wb + 262144;
  unsigned short* v_wb   = k_wb + 262144;
  unsigned short* m_wb   = v_wb + 262144;
  unsigned short* mlp_wb = m_wb + 262144;
  unsigned short* w2b    = mlp_wb + 524288;
  unsigned short* wob    = w2b + 8192;
  unsigned short* xcg    = att0t;  // dead before attention
  unsigned short* SbU = (unsigned short*)ws;  // bf16 S (B,NP,NP): slots 0..2 (dead after mlp)
  int*   idx0 = (int*)(ws + 10 * SLOT);
  int*   idx1 = idx0 + BATCH * NP * KNNK;
  float* colM = ws + 10 * SLOT + 327680;
  float* colS = colM + BATCH * NP * 8;
  float* weights = colS + BATCH * NP * 8;
  float* wsum = weights + BATCH * NP;
  float* wtg  = wsum + BATCH;
  float* cent = wtg + BATCH * 3 * NP;
  float* Hmb  = cent + BATCH * 6;
  float* upot = Hmb + BATCH * 9;
  float* vpot = upot + BATCH * NP;
  int*   scnt = (int*)(vpot + BATCH * NP);  // 5 iteration counters (zeroed in convknn)

  // 0+1. merged kNN + weight conversions + vpot zero + counter zero (one dispatch)
  convknn_kernel<<<4096 + 1649, 256, 0, stream>>>(src, tgt, idx0, idx1,
                                                  q_w, k_w, v_w, m_w, mlp_w, g_w2, g_wo,
                                                  q_wb, k_wb, v_wb, m_wb, mlp_wb, w2b, wob,
                                                  vpot, scnt);
  // 2. GAC -> xcg -> d0t/d1t
  gac4_kernel<<<2 * BATCH * NP / 4, 256, 0, stream>>>(src, tgt, idx0, idx1, g_w1, g_s1, g_b1,
                                                      w2b, g_s2, g_b2, xcg);
  dim3 gg(2 * BATCH * NP / 128, DEMB / 128);
  gacproj_kernel<<<gg, 256, 0, stream>>>(wob, g_so, g_bo, xcg, d0t, d1t);
  // 3. Q/K/V projections (merged 6-in-1; Q pre-scaled)
  dim3 gqkv(NP / 128, DEMB / 128, 24);
  qkv_kernel<<<gqkv, 256, 0, stream>>>(q_wb, k_wb, v_wb, q_b, k_b, v_b, d0t, d1t,
                                       Q0, K0, V0, Q1, K1, V1);
  // 4. cross attention (R13-proven)
  attn_mfma_kernel<<<2 * 16 * 16, 256, 0, stream>>>(Q0, K0, V0, Q1, K1, V1, att0t, att1t);
  // 5. message projection (both sides, one dispatch)
  dim3 gq8(NP / 128, DEMB / 128, 8);
  proj_mfma_kernel<3, 512><<<gq8, 256, 0, stream>>>(m_wb, m_b, att0t, att1t, nullptr, nullptr,
                                                    nullptr, nullptr, mp0t, mp1t);
  // 6. MLP + residual (both sides, one dispatch)
  proj_mfma_kernel<4, 1024><<<gq8, 256, 0, stream>>>(mlp_wb, nullptr, d0t, d1t, mp0t, mp1t,
                                                     d0t, d1t, d0nt, d1nt);
  // 7. dists -> bf16 S
  dists_mfma_kernel<<<dim3(NP / 128, NP / 128, BATCH), 256, 0, stream>>>(d0nt, d1nt, SbU);
  // 8. sinkhorn via potentials, 5 iterations (c2 fused into c1 via last-block pattern)
  for (int it = 0; it < 5; ++it) {
    sink_u_kernel<<<BATCH * NP / 4, 256, 0, stream>>>(SbU, vpot, upot);
    sink_c1_kernel<<<dim3(NP / 128, 8, BATCH), 256, 0, stream>>>(SbU, upot, colM, colS,
                                                                 vpot, scnt + it);
  }
  // 9. perm_norm (to out) + weights + weighted_tgt (wave-per-row, barrier-free)
  perm_kernel<<<BATCH * NP / 4, 256, 0, stream>>>(SbU, upot, vpot, tgt, out + 48, weights, wtg);
  // 10. Kabsch fully fused (cent+Hm+solve, 1 block/batch)
  cent_hm_solve_kernel<<<BATCH, 256, 0, stream>>>(src, wtg, weights, out);
}

// Round 20
// 613.165 us; speedup vs baseline: 1.5560x; 1.5560x over previous
//
#include <hip/hip_runtime.h>
#include <math.h>

#define BATCH 4
#define NP    2048
#define KNNK  20
#define DEMB  512
#define NH    4
#define DHD   128

typedef __attribute__((ext_vector_type(8))) short bf16x8;
typedef __attribute__((ext_vector_type(4))) float f32x4;

__device__ __forceinline__ unsigned short f2b(float f) {
  unsigned u = __builtin_bit_cast(unsigned, f);
  u += 0x7FFF + ((u >> 16) & 1);
  return (unsigned short)(u >> 16);
}
__device__ __forceinline__ float b2f(unsigned short u) {
  unsigned v = ((unsigned)u) << 16;
  return __builtin_bit_cast(float, v);
}

__device__ __forceinline__ void gload_lds16(const void* g, void* l) {
  __builtin_amdgcn_global_load_lds(
      (const __attribute__((address_space(1))) unsigned int*)g,
      (__attribute__((address_space(3))) unsigned int*)l, 16, 0, 0);
}

// ---------------------------------------------------------------- merged kNN + weight-conv (block-range split)
__global__ __launch_bounds__(256) void convknn_kernel(
    const float* __restrict__ x0, const float* __restrict__ x1,
    int* __restrict__ io0, int* __restrict__ io1,
    const float* __restrict__ s0, const float* __restrict__ s1,
    const float* __restrict__ s2, const float* __restrict__ s3,
    const float* __restrict__ s4, const float* __restrict__ s5,
    const float* __restrict__ s6,
    unsigned short* __restrict__ d0, unsigned short* __restrict__ d1,
    unsigned short* __restrict__ d2, unsigned short* __restrict__ d3,
    unsigned short* __restrict__ d4, unsigned short* __restrict__ d5,
    unsigned short* __restrict__ d6, float* __restrict__ vpot) {
  __shared__ float xs0[NP], xs1[NP], xs2[NP];
  if (blockIdx.x >= 4096) {
    // ---- weight conversion path (blocks 4096..5743)
    int i4 = ((blockIdx.x - 4096) * 256 + threadIdx.x) * 4;
    const float* src; unsigned short* dst; int off;
    if      (i4 < 262144)  { src = s0; dst = d0; off = i4; }
    else if (i4 < 524288)  { src = s1; dst = d1; off = i4 - 262144; }
    else if (i4 < 786432)  { src = s2; dst = d2; off = i4 - 524288; }
    else if (i4 < 1048576) { src = s3; dst = d3; off = i4 - 786432; }
    else if (i4 < 1572864) { src = s4; dst = d4; off = i4 - 1048576; }
    else if (i4 < 1581056) { src = s5; dst = d5; off = i4 - 1572864; }
    else if (i4 < 1679360) { src = s6; dst = d6; off = i4 - 1581056; }
    else if (i4 < 1687552) {
      off = i4 - 1679360;
      *(float4*)(vpot + off) = (float4){0.f, 0.f, 0.f, 0.f};
      return;
    } else return;
    float4 v = *(const float4*)(src + off);
    dst[off] = f2b(v.x); dst[off + 1] = f2b(v.y);
    dst[off + 2] = f2b(v.z); dst[off + 3] = f2b(v.w);
    return;
  }
  // ---- kNN path (blocks 0..4095)
  int which = blockIdx.x >> 11;
  int inner = blockIdx.x & 2047;
  const float* x = which ? x1 : x0;
  int* idx_out = which ? io1 : io0;
  int b = inner >> 9;
  int p0 = (inner & 511) * 4;
  int t = threadIdx.x, w = t >> 6, lane = t & 63;
  const float* xb = x + (size_t)b * 3 * NP;
  for (int m = t; m < NP; m += 256) {
    xs0[m] = xb[m]; xs1[m] = xb[NP + m]; xs2[m] = xb[2 * NP + m];
  }
  __syncthreads();
  int n = p0 + w;
  float c0 = xs0[n], c1 = xs1[n], c2 = xs2[n];
  float xxn = c0 * c0 + c1 * c1 + c2 * c2;
  float nd[32];
#pragma unroll
  for (int i = 0; i < 32; ++i) {
    int m = i * 64 + lane;
    float a0 = xs0[m], a1 = xs1[m], a2 = xs2[m];
    nd[i] = 2.f * (c0 * a0 + c1 * a1 + c2 * a2) - xxn - (a0 * a0 + a1 * a1 + a2 * a2);
  }
  unsigned sel = 0u;
  int* orow = idx_out + ((size_t)b * NP + n) * KNNK;
  for (int it = 0; it < KNNK; ++it) {
    float bv = -INFINITY; int bi = 0x7fffffff;
#pragma unroll
    for (int i = 0; i < 32; ++i) {
      float v = ((sel >> i) & 1u) ? -INFINITY : nd[i];
      if (v > bv) { bv = v; bi = i * 64 + lane; }
    }
#pragma unroll
    for (int s = 1; s < 64; s <<= 1) {
      float ov = __shfl_xor(bv, s);
      int oi = __shfl_xor(bi, s);
      if (ov > bv || (ov == bv && oi < bi)) { bv = ov; bi = oi; }
    }
    if (lane == 0) orow[it] = bi;
    if (lane == (bi & 63)) sel |= (1u << (bi >> 6));
  }
}

// ---------------------------------------------------------------- fused GAC (merged src/tgt)
__global__ __launch_bounds__(256) void gac4_kernel(
    const float* __restrict__ x0, const float* __restrict__ x1,
    const int* __restrict__ io0, const int* __restrict__ io1,
    const float* __restrict__ w1, const float* __restrict__ s1, const float* __restrict__ b1,
    const unsigned short* __restrict__ w2b, const float* __restrict__ s2,
    const float* __restrict__ b2, unsigned short* __restrict__ xcg_all) {
  __shared__ __align__(16) float w1p[448];
  __shared__ float s1s[64], b1s[64];
  __shared__ float g[4][6][20];
  __shared__ __align__(16) float h1f[4][20][65];
  __shared__ __align__(16) unsigned short h1b[4 * 2048];
  int which = blockIdx.x >> 11;
  int inner = blockIdx.x & 2047;
  const float* x = which ? x1 : x0;
  const int* idx = which ? io1 : io0;
  unsigned short* xcg = xcg_all + (size_t)which * BATCH * NP * 192;
  int t = threadIdx.x, w = t >> 6, lane = t & 63;
  int lr = lane & 15, lg = lane >> 4;
  int b = inner >> 9;
  int n0g = (inner & 511) * 4;
  int pbase = b * NP + n0g;
  const float* xb = x + (size_t)b * 3 * NP;

  for (int i = t; i < 384; i += 256) { int o = i / 6, c = i % 6; w1p[o * 7 + c] = w1[i]; }
  if (t < 64) { s1s[t] = s1[t]; b1s[t] = b1[t]; }
  if (t < 80) {
    int p = t / 20, k = t % 20;
    int n = n0g + p;
    int j = idx[((size_t)b * NP + n) * KNNK + k];
    float c0 = xb[n], c1 = xb[NP + n], c2 = xb[2 * NP + n];
    g[p][0][k] = xb[j] - c0; g[p][1][k] = xb[NP + j] - c1; g[p][2][k] = xb[2 * NP + j] - c2;
    g[p][3][k] = c0; g[p][4][k] = c1; g[p][5][k] = c2;
  }
  for (int i = t; i < 4 * 12 * 32; i += 256) {
    int p = i / 384, rem = i % 384;
    ((unsigned*)h1b)[p * 1024 + (20 + rem / 32) * 32 + (rem & 31)] = 0u;
  }
  __syncthreads();

#pragma unroll
  for (int pass = 0; pass < 20; ++pass) {
    int item = pass * 256 + t;
    int o = item & 63, kp = item >> 6;
    int k = kp % 20, p = kp / 20;
    float y = 0.f;
#pragma unroll
    for (int c = 0; c < 6; ++c) y += w1p[o * 7 + c] * g[p][c][k];
    y = fmaxf(y * s1s[o] + b1s[o], 0.f);
    h1f[p][k][o] = y;
    h1b[p * 2048 + k * 64 + (((o >> 3) ^ (k & 7)) << 3) + (o & 7)] = f2b(y);
  }
  __syncthreads();

  {
    int p = w, o = lane;
    float mx = -INFINITY;
#pragma unroll
    for (int k = 0; k < 20; ++k) mx = fmaxf(mx, h1f[p][k][o]);
    float se = 0.f, sh = 0.f;
#pragma unroll
    for (int k = 0; k < 20; ++k) {
      float h = h1f[p][k][o];
      float e = __expf(h - mx);
      se += e; sh += h * e;
    }
    xcg[(size_t)(pbase + p) * 192 + o] = f2b(sh / se);
  }

  bf16x8 bfrag[2][2];
#pragma unroll
  for (int ks = 0; ks < 2; ++ks)
#pragma unroll
    for (int nt = 0; nt < 2; ++nt) {
      int kcol = nt * 16 + lr;
      int oc = ks * 4 + lg;
      bfrag[ks][nt] = *(const bf16x8*)&h1b[w * 2048 + kcol * 64 + ((oc ^ (kcol & 7)) << 3)];
    }
  f32x4 acc[8][2];
#pragma unroll
  for (int i = 0; i < 8; ++i) { acc[i][0] = (f32x4){0,0,0,0}; acc[i][1] = (f32x4){0,0,0,0}; }
#pragma unroll
  for (int i = 0; i < 8; ++i)
#pragma unroll
    for (int ks = 0; ks < 2; ++ks) {
      bf16x8 a = *(const bf16x8*)(w2b + (i * 16 + lr) * 64 + ks * 32 + lg * 8);
      acc[i][0] = __builtin_amdgcn_mfma_f32_16x16x32_bf16(a, bfrag[ks][0], acc[i][0], 0, 0, 0);
      acc[i][1] = __builtin_amdgcn_mfma_f32_16x16x32_bf16(a, bfrag[ks][1], acc[i][1], 0, 0, 0);
    }
  int pt = pbase + w;
#pragma unroll
  for (int i = 0; i < 8; ++i) {
    float x2o[4];
#pragma unroll
    for (int r = 0; r < 4; ++r) {
      int o = i * 16 + lg * 4 + r;
      float sv = s2[o], bv = b2[o];
      float v0 = fmaxf(acc[i][0][r] * sv + bv, 0.f);
      float v1 = fmaxf(acc[i][1][r] * sv + bv, 0.f);
      float vm = (lr < 4) ? fmaxf(v0, v1) : v0;
#pragma unroll
      for (int s = 1; s < 16; s <<= 1) vm = fmaxf(vm, __shfl_xor(vm, s));
      float e0 = __expf(v0 - vm);
      float e1 = (lr < 4) ? __expf(v1 - vm) : 0.f;
      float se = e0 + e1, sh = v0 * e0 + v1 * e1;
#pragma unroll
      for (int s = 1; s < 16; s <<= 1) { se += __shfl_xor(se, s); sh += __shfl_xor(sh, s); }
      x2o[r] = sh / se;
    }
    if (lr == 0) {
      ushort4 pk;
      pk.x = f2b(x2o[0]); pk.y = f2b(x2o[1]); pk.z = f2b(x2o[2]); pk.w = f2b(x2o[3]);
      *(ushort4*)&xcg[(size_t)pt * 192 + 64 + i * 16 + lg * 4] = pk;
    }
  }
}

// ---------------------------------------------------------------- GAC out-proj MFMA (merged)
__global__ __launch_bounds__(256, 2) void gacproj_kernel(
    const unsigned short* __restrict__ wob, const float* __restrict__ so,
    const float* __restrict__ bo, const unsigned short* __restrict__ xcg,
    unsigned short* __restrict__ Y0, unsigned short* __restrict__ Y1) {
  __shared__ __align__(16) unsigned short Al[128 * 64];
  __shared__ __align__(16) unsigned short Bl[128 * 64];
  int n0 = blockIdx.x * 128, o0 = blockIdx.y * 128;
  unsigned short* Yt = (n0 < BATCH * NP) ? Y0 : Y1;
  int nbase = n0 & (BATCH * NP - 1);
  int tid = threadIdx.x, w = tid >> 6, lane = tid & 63;
  int lr = lane & 15, lg = lane >> 4;
  int wa = w >> 1, wb = w & 1;
  f32x4 acc[4][4];
#pragma unroll
  for (int i = 0; i < 4; ++i)
#pragma unroll
    for (int j = 0; j < 4; ++j) acc[i][j] = (f32x4){0.f, 0.f, 0.f, 0.f};

  for (int k0 = 0; k0 < 192; k0 += 64) {
    __syncthreads();
#pragma unroll
    for (int u = 0; u < 4; ++u) {
      int C = u * 256 + tid;
      int row = C >> 3, j = C & 7;
      int js = j ^ (row & 7);
      gload_lds16(wob + (size_t)(o0 + row) * 192 + k0 + js * 8, Al + (u * 256 + w * 64) * 8);
      gload_lds16(xcg + (size_t)(n0 + row) * 192 + k0 + js * 8, Bl + (u * 256 + w * 64) * 8);
    }
    asm volatile("s_waitcnt vmcnt(0)" ::: "memory");
    __syncthreads();
#pragma unroll
    for (int kk = 0; kk < 2; ++kk) {
      bf16x8 af[4], bfr[4];
#pragma unroll
      for (int i = 0; i < 4; ++i) {
        int rowa = wa * 64 + i * 16 + lr;
        int ca = (kk * 4 + lg) ^ (rowa & 7);
        af[i] = *(const bf16x8*)(Al + rowa * 64 + ca * 8);
        int rowb = wb * 64 + i * 16 + lr;
        int cb = (kk * 4 + lg) ^ (rowb & 7);
        bfr[i] = *(const bf16x8*)(Bl + rowb * 64 + cb * 8);
      }
#pragma unroll
      for (int i = 0; i < 4; ++i)
#pragma unroll
        for (int j = 0; j < 4; ++j)
          acc[i][j] = __builtin_amdgcn_mfma_f32_16x16x32_bf16(af[i], bfr[j], acc[i][j], 0, 0, 0);
    }
  }
#pragma unroll
  for (int i = 0; i < 4; ++i) {
#pragma unroll
    for (int j = 0; j < 4; ++j) {
      int obase = o0 + wa * 64 + i * 16 + lg * 4;
      int n = nbase + wb * 64 + j * 16 + lr;
      ushort4 pk;
      pk.x = f2b(fmaxf(acc[i][j][0] * so[obase] + bo[obase], 0.f));
      pk.y = f2b(fmaxf(acc[i][j][1] * so[obase + 1] + bo[obase + 1], 0.f));
      pk.z = f2b(fmaxf(acc[i][j][2] * so[obase + 2] + bo[obase + 2], 0.f));
      pk.w = f2b(fmaxf(acc[i][j][3] * so[obase + 3] + bo[obase + 3], 0.f));
      *(ushort4*)&Yt[(size_t)n * DEMB + obase] = pk;
    }
  }
}

// ---------------------------------------------------------------- merged Q/K/V projection (6-in-1)
__global__ __launch_bounds__(256, 2) void qkv_kernel(
    const unsigned short* __restrict__ qw, const unsigned short* __restrict__ kw,
    const unsigned short* __restrict__ vw, const float* __restrict__ qbias,
    const float* __restrict__ kbias, const float* __restrict__ vbias,
    const unsigned short* __restrict__ d0t, const unsigned short* __restrict__ d1t,
    unsigned short* __restrict__ Q0, unsigned short* __restrict__ K0,
    unsigned short* __restrict__ V0, unsigned short* __restrict__ Q1,
    unsigned short* __restrict__ K1, unsigned short* __restrict__ V1) {
  __shared__ __align__(16) unsigned short Al[128 * 64];
  __shared__ __align__(16) unsigned short Bl[128 * 64];
  int z = blockIdx.z;
  int b = z & 3, which = z >> 2;
  int proj = which % 3, side = which / 3;
  const unsigned short* Wb = (proj == 0) ? qw : (proj == 1) ? kw : vw;
  const float* bias = (proj == 0) ? qbias : (proj == 1) ? kbias : vbias;
  const unsigned short* Bt = side ? d1t : d0t;
  unsigned short* Y = (which == 0) ? Q0 : (which == 1) ? K0 : (which == 2) ? V0
                    : (which == 3) ? Q1 : (which == 4) ? K1 : V1;
  float pscale = (proj == 0) ? 0.08838834764831845f : 1.f;
  int n0 = blockIdx.x * 128, o0 = blockIdx.y * 128;
  int tid = threadIdx.x, w = tid >> 6, lane = tid & 63;
  int lr = lane & 15, lg = lane >> 4;
  int wa = w >> 1, wb = w & 1;
  f32x4 acc[4][4];
#pragma unroll
  for (int i = 0; i < 4; ++i)
#pragma unroll
    for (int j = 0; j < 4; ++j) acc[i][j] = (f32x4){0.f, 0.f, 0.f, 0.f};

  for (int k0 = 0; k0 < DEMB; k0 += 64) {
    __syncthreads();
#pragma unroll
    for (int u = 0; u < 4; ++u) {
      int C = u * 256 + tid;
      int row = C >> 3, j = C & 7;
      int js = j ^ (row & 7);
      gload_lds16(Wb + (size_t)(o0 + row) * DEMB + k0 + js * 8, Al + (u * 256 + w * 64) * 8);
      gload_lds16(Bt + ((size_t)b * NP + n0 + row) * 512 + k0 + js * 8,
                  Bl + (u * 256 + w * 64) * 8);
    }
    asm volatile("s_waitcnt vmcnt(0)" ::: "memory");
    __syncthreads();
#pragma unroll
    for (int kk = 0; kk < 2; ++kk) {
      bf16x8 af[4], bfr[4];
#pragma unroll
      for (int i = 0; i < 4; ++i) {
        int rowa = wa * 64 + i * 16 + lr;
        int ca = (kk * 4 + lg) ^ (rowa & 7);
        af[i] = *(const bf16x8*)(Al + rowa * 64 + ca * 8);
        int rowb = wb * 64 + i * 16 + lr;
        int cb = (kk * 4 + lg) ^ (rowb & 7);
        bfr[i] = *(const bf16x8*)(Bl + rowb * 64 + cb * 8);
      }
#pragma unroll
      for (int i = 0; i < 4; ++i)
#pragma unroll
        for (int j = 0; j < 4; ++j)
          acc[i][j] = __builtin_amdgcn_mfma_f32_16x16x32_bf16(af[i], bfr[j], acc[i][j], 0, 0, 0);
    }
  }
#pragma unroll
  for (int i = 0; i < 4; ++i) {
#pragma unroll
    for (int j = 0; j < 4; ++j) {
#pragma unroll
      for (int r = 0; r < 4; ++r) {
        int o = o0 + wa * 64 + i * 16 + lg * 4 + r;
        int n = n0 + wb * 64 + j * 16 + lr;
        float v = (acc[i][j][r] + bias[o]) * pscale;
        int h = o & 3, dh = o >> 2;
        if (proj < 2) {
          Y[(((size_t)b * NH + h) * NP + n) * DHD + dh] = f2b(v);
        } else {
          Y[(((size_t)b * NH + h) * DHD + dh) * NP + n] = f2b(v);
        }
      }
    }
  }
}

// ---------------------------------------------------------------- MFMA projection GEMM, dual-side
template <int MODE, int KD>
__global__ __launch_bounds__(256, 2) void proj_mfma_kernel(
    const unsigned short* __restrict__ Wb, const float* __restrict__ bias,
    const unsigned short* __restrict__ Bt0, const unsigned short* __restrict__ Bt1,
    const unsigned short* __restrict__ Bt2_0, const unsigned short* __restrict__ Bt2_1,
    const unsigned short* __restrict__ D0, const unsigned short* __restrict__ D1,
    unsigned short* __restrict__ Y0, unsigned short* __restrict__ Y1) {
  __shared__ __align__(16) unsigned short Al[128 * 64];
  __shared__ __align__(16) unsigned short Bl[128 * 64];
  int z = blockIdx.z;
  int b = z & 3, side = z >> 2;
  const unsigned short* Bt = side ? Bt1 : Bt0;
  const unsigned short* Bt2 = side ? Bt2_1 : Bt2_0;
  const unsigned short* Dres = side ? D1 : D0;
  unsigned short* Y = side ? Y1 : Y0;
  int n0 = blockIdx.x * 128, o0 = blockIdx.y * 128;
  int tid = threadIdx.x, w = tid >> 6, lane = tid & 63;
  int lr = lane & 15, lg = lane >> 4;
  int wa = w >> 1, wb = w & 1;
  f32x4 acc[4][4];
#pragma unroll
  for (int i = 0; i < 4; ++i)
#pragma unroll
    for (int j = 0; j < 4; ++j) acc[i][j] = (f32x4){0.f, 0.f, 0.f, 0.f};

  for (int k0 = 0; k0 < KD; k0 += 64) {
    __syncthreads();
    const unsigned short* srcB; int kc;
    if (MODE == 4) { srcB = (k0 < 512) ? Bt : Bt2; kc = k0 & 511; }
    else { srcB = Bt; kc = k0; }
#pragma unroll
    for (int u = 0; u < 4; ++u) {
      int C = u * 256 + tid;
      int row = C >> 3, j = C & 7;
      int js = j ^ (row & 7);
      gload_lds16(Wb + (size_t)(o0 + row) * KD + k0 + js * 8, Al + (u * 256 + w * 64) * 8);
      gload_lds16(srcB + ((size_t)b * NP + n0 + row) * 512 + kc + js * 8,
                  Bl + (u * 256 + w * 64) * 8);
    }
    asm volatile("s_waitcnt vmcnt(0)" ::: "memory");
    __syncthreads();
#pragma unroll
    for (int kk = 0; kk < 2; ++kk) {
      bf16x8 af[4], bfr[4];
#pragma unroll
      for (int i = 0; i < 4; ++i) {
        int rowa = wa * 64 + i * 16 + lr;
        int ca = (kk * 4 + lg) ^ (rowa & 7);
        af[i] = *(const bf16x8*)(Al + rowa * 64 + ca * 8);
        int rowb = wb * 64 + i * 16 + lr;
        int cb = (kk * 4 + lg) ^ (rowb & 7);
        bfr[i] = *(const bf16x8*)(Bl + rowb * 64 + cb * 8);
      }
#pragma unroll
      for (int i = 0; i < 4; ++i)
#pragma unroll
        for (int j = 0; j < 4; ++j)
          acc[i][j] = __builtin_amdgcn_mfma_f32_16x16x32_bf16(af[i], bfr[j], acc[i][j], 0, 0, 0);
    }
  }
#pragma unroll
  for (int i = 0; i < 4; ++i) {
#pragma unroll
    for (int j = 0; j < 4; ++j) {
#pragma unroll
      for (int r = 0; r < 4; ++r) {
        int o = o0 + wa * 64 + i * 16 + lg * 4 + r;
        int n = n0 + wb * 64 + j * 16 + lr;
        float v = acc[i][j][r];
        if (MODE == 3) {
          v += bias[o];
        } else {
          v += b2f(Dres[((size_t)b * NP + n) * DEMB + o]);
        }
        Y[((size_t)b * NP + n) * DEMB + o] = f2b(v);
      }
    }
  }
}

// ---------------------------------------------------------------- MFMA flash attention (R13-proven)
__global__ __launch_bounds__(256, 2) void attn_mfma_kernel(
    const unsigned short* __restrict__ Q0, const unsigned short* __restrict__ K0,
    const unsigned short* __restrict__ V0, const unsigned short* __restrict__ Q1,
    const unsigned short* __restrict__ K1, const unsigned short* __restrict__ V1,
    unsigned short* __restrict__ att0, unsigned short* __restrict__ att1) {
  __shared__ __align__(16) unsigned short Klds[2][8192];
  __shared__ __align__(16) unsigned short Vlds[2][8192];
  __shared__ __align__(16) float Pws[4][544];

  int hw = blockIdx.x;                       // grid = 512, 512 % 8 == 0
  int lid = ((hw & 7) << 6) + (hw >> 3);     // bijective XCD swizzle
  int which = lid >> 8;
  int blk = lid & 255;
  const unsigned short* Qb = which ? Q1 : Q0;
  const unsigned short* Kb = which ? K0 : K1;
  const unsigned short* Vb = which ? V0 : V1;
  unsigned short* att = which ? att1 : att0;

  int bh = blk >> 4, qt = blk & 15;
  int tid = threadIdx.x;
  int w = tid >> 6, lane = tid & 63;
  int lr = lane & 15, lg = lane >> 4;
  int q0 = qt * 128 + w * 32;

  bf16x8 qf[2][4];
#pragma unroll
  for (int f = 0; f < 2; ++f) {
    const unsigned short* Qrow = Qb + ((size_t)bh * NP + q0 + f * 16 + lr) * DHD + lg * 8;
#pragma unroll
    for (int ds = 0; ds < 4; ++ds) qf[f][ds] = *(const bf16x8*)(Qrow + ds * 32);
  }

  const unsigned short* Kg = Kb + (size_t)bh * NP * DHD;
  const unsigned short* Vg = Vb + (size_t)bh * DHD * NP;
  unsigned short* Pl = (unsigned short*)&Pws[w][0];

  f32x4 o[2][8];
#pragma unroll
  for (int f = 0; f < 2; ++f)
#pragma unroll
    for (int ds = 0; ds < 8; ++ds) o[f][ds] = (f32x4){0.f, 0.f, 0.f, 0.f};
  float mrun[2][4], lrun[2][4];
#pragma unroll
  for (int f = 0; f < 2; ++f)
#pragma unroll
    for (int r = 0; r < 4; ++r) { mrun[f][r] = -INFINITY; lrun[f][r] = 0.f; }

  // prologue: stage tile 0 into buffer 0
#pragma unroll
  for (int u = 0; u < 4; ++u) {
    int C = (w * 4 + u) * 64 + lane;
    int key = C >> 4, jl = C & 15, j = jl ^ (key & 15);
    gload_lds16(Kg + (size_t)key * DHD + j * 8, &Klds[0][(w * 4 + u) * 512]);
    int d = C >> 3, jv = (C & 7) ^ (d & 7);
    gload_lds16(Vg + (size_t)d * NP + jv * 8, &Vlds[0][(w * 4 + u) * 512]);
  }
  asm volatile("s_waitcnt vmcnt(0)" ::: "memory");
  __syncthreads();

  for (int tIdx = 0; tIdx < 32; ++tIdx) {
    int cur = tIdx & 1;
    // stage next tile into the other buffer (async, no wait)
    if (tIdx < 31) {
      int kv0 = (tIdx + 1) * 64;
#pragma unroll
      for (int u = 0; u < 4; ++u) {
        int C = (w * 4 + u) * 64 + lane;
        int key = C >> 4, jl = C & 15, j = jl ^ (key & 15);
        gload_lds16(Kg + (size_t)(kv0 + key) * DHD + j * 8, &Klds[cur ^ 1][(w * 4 + u) * 512]);
        int d = C >> 3, jv = (C & 7) ^ (d & 7);
        gload_lds16(Vg + (size_t)d * NP + kv0 + jv * 8, &Vlds[cur ^ 1][(w * 4 + u) * 512]);
      }
    }
    // QK^T for both fragments (K-fragments loaded once, shared)
    __builtin_amdgcn_s_setprio(1);
    f32x4 s[2][4];
#pragma unroll
    for (int ks = 0; ks < 4; ++ks) {
      s[0][ks] = (f32x4){0.f, 0.f, 0.f, 0.f};
      s[1][ks] = (f32x4){0.f, 0.f, 0.f, 0.f};
      int key = ks * 16 + lr;
#pragma unroll
      for (int dstep = 0; dstep < 4; ++dstep) {
        int dbyte = (lg * 16 + dstep * 64) ^ ((key & 15) << 4);
        bf16x8 kb = *(const bf16x8*)(&Klds[cur][0] + key * 128 + (dbyte >> 1));
        s[0][ks] = __builtin_amdgcn_mfma_f32_16x16x32_bf16(qf[0][dstep], kb, s[0][ks], 0, 0, 0);
        s[1][ks] = __builtin_amdgcn_mfma_f32_16x16x32_bf16(qf[1][dstep], kb, s[1][ks], 0, 0, 0);
      }
    }
    __builtin_amdgcn_s_setprio(0);
    // online softmax with defer-max (both fragments); max reduce only
    float tmax[2][4];
#pragma unroll
    for (int f = 0; f < 2; ++f)
#pragma unroll
      for (int r = 0; r < 4; ++r) {
        float m = fmaxf(fmaxf(s[f][0][r], s[f][1][r]), fmaxf(s[f][2][r], s[f][3][r]));
#pragma unroll
        for (int msk = 1; msk < 16; msk <<= 1) m = fmaxf(m, __shfl_xor(m, msk));
        tmax[f][r] = m;
      }
    int need = 0;
#pragma unroll
    for (int f = 0; f < 2; ++f)
#pragma unroll
      for (int r = 0; r < 4; ++r) need |= (tmax[f][r] > mrun[f][r]) ? 1 : 0;
    float fac[2][4];
#pragma unroll
    for (int f = 0; f < 2; ++f)
#pragma unroll
      for (int r = 0; r < 4; ++r) fac[f][r] = 1.f;
    if (__any(need)) {
#pragma unroll
      for (int f = 0; f < 2; ++f)
#pragma unroll
        for (int r = 0; r < 4; ++r) {
          float mnew = fmaxf(mrun[f][r], tmax[f][r]);
          fac[f][r] = __expf(mrun[f][r] - mnew);
          mrun[f][r] = mnew;
        }
#pragma unroll
      for (int f = 0; f < 2; ++f)
#pragma unroll
        for (int ds = 0; ds < 8; ++ds)
#pragma unroll
          for (int r = 0; r < 4; ++r) o[f][ds][r] *= fac[f][r];
    }
    // per-fragment: P write + per-lane partial sum + PV
#pragma unroll
    for (int f = 0; f < 2; ++f) {
      float ps[4] = {0.f, 0.f, 0.f, 0.f};
#pragma unroll
      for (int ks = 0; ks < 4; ++ks) {
        int k = ks * 16 + lr;
#pragma unroll
        for (int r = 0; r < 4; ++r) {
          float p = __expf(s[f][ks][r] - mrun[f][r]);
          ps[r] += p;
          int q = lg * 4 + r;
          int kbyte = (k * 2) ^ ((q & 7) << 4);
          Pl[q * 64 + (kbyte >> 1)] = f2b(p);
        }
      }
#pragma unroll
      for (int r = 0; r < 4; ++r)
        lrun[f][r] = lrun[f][r] * fac[f][r] + ps[r];
      __builtin_amdgcn_s_setprio(1);
#pragma unroll
      for (int ks2 = 0; ks2 < 2; ++ks2) {
        int kbyte = ((lg * 8 + ks2 * 32) * 2) ^ ((lr & 7) << 4);
        bf16x8 pa = *(const bf16x8*)(Pl + lr * 64 + (kbyte >> 1));
#pragma unroll
        for (int ds = 0; ds < 8; ++ds) {
          int d = ds * 16 + lr;
          int keybyte = ((lg * 8 + ks2 * 32) * 2) ^ ((d & 7) << 4);
          bf16x8 vb = *(const bf16x8*)(&Vlds[cur][0] + d * 64 + (keybyte >> 1));
          o[f][ds] = __builtin_amdgcn_mfma_f32_16x16x32_bf16(pa, vb, o[f][ds], 0, 0, 0);
        }
      }
      __builtin_amdgcn_s_setprio(0);
    }
    asm volatile("s_waitcnt vmcnt(0)" ::: "memory");
    __syncthreads();
  }

  // final sum reduce (once, not per tile)
#pragma unroll
  for (int f = 0; f < 2; ++f)
#pragma unroll
    for (int r = 0; r < 4; ++r) {
      float s = lrun[f][r];
#pragma unroll
      for (int msk = 1; msk < 16; msk <<= 1) s += __shfl_xor(s, msk);
      lrun[f][r] = s;
    }

  int b = bh >> 2, h = bh & 3;
  float* ost = &Pws[w][0];
#pragma unroll
  for (int f = 0; f < 2; ++f) {
    float linv[4];
#pragma unroll
    for (int r = 0; r < 4; ++r) linv[r] = 1.f / lrun[f][r];
    unsigned short* outb = att + ((size_t)b * NP + q0 + f * 16) * DEMB;
#pragma unroll
    for (int c = 0; c < 4; ++c) {
#pragma unroll
      for (int half = 0; half < 2; ++half) {
        int ds = 2 * c + half;
#pragma unroll
        for (int r = 0; r < 4; ++r)
          ost[(lg * 4 + r) * 33 + half * 16 + lr] = o[f][ds][r] * linv[r];
      }
#pragma unroll
      for (int it = 0; it < 8; ++it) {
        int q = lr, dl = it * 4 + lg;
        int d = c * 32 + dl;
        outb[(size_t)q * DEMB + d * 4 + h] = f2b(ost[q * 33 + dl]);
      }
    }
  }
}

// ---------------------------------------------------------------- dists: bf16 MFMA GEMM -> bf16 S (B,NP,NP)
__global__ __launch_bounds__(256, 2) void dists_mfma_kernel(
    const unsigned short* __restrict__ At, const unsigned short* __restrict__ Bt,
    unsigned short* __restrict__ S) {
  __shared__ __align__(16) unsigned short Sh[2][8192];
  int b = blockIdx.z;
  int n0 = blockIdx.y * 128, m0 = blockIdx.x * 128;
  int tid = threadIdx.x, w = tid >> 6, lane = tid & 63;
  int lr = lane & 15, lg = lane >> 4;
  int wn = w >> 1, wm = w & 1;
  const unsigned short* Ab = At + ((size_t)b * NP + n0) * DEMB;
  const unsigned short* Bb = Bt + ((size_t)b * NP + m0) * DEMB;
  f32x4 acc[4][4];
#pragma unroll
  for (int i = 0; i < 4; ++i)
#pragma unroll
    for (int j = 0; j < 4; ++j) acc[i][j] = (f32x4){0.f, 0.f, 0.f, 0.f};

  for (int k0 = 0; k0 < DEMB; k0 += 64) {
    __syncthreads();
#pragma unroll
    for (int u = 0; u < 4; ++u) {
      int C = u * 256 + tid;
      int row = C >> 3, j = C & 7;
      int js = j ^ (row & 7);
      gload_lds16(Ab + (size_t)row * DEMB + k0 + js * 8, &Sh[0][(u * 256 + w * 64) * 8]);
      gload_lds16(Bb + (size_t)row * DEMB + k0 + js * 8, &Sh[1][(u * 256 + w * 64) * 8]);
    }
    asm volatile("s_waitcnt vmcnt(0)" ::: "memory");
    __syncthreads();
#pragma unroll
    for (int kk = 0; kk < 2; ++kk) {
      bf16x8 af[4], bfr[4];
#pragma unroll
      for (int i = 0; i < 4; ++i) {
        int rowa = wn * 64 + i * 16 + lr;
        int ca = (kk * 4 + lg) ^ (rowa & 7);
        af[i] = *(const bf16x8*)(&Sh[0][0] + rowa * 64 + ca * 8);
        int rowb = wm * 64 + i * 16 + lr;
        int cb = (kk * 4 + lg) ^ (rowb & 7);
        bfr[i] = *(const bf16x8*)(&Sh[1][0] + rowb * 64 + cb * 8);
      }
#pragma unroll
      for (int i = 0; i < 4; ++i)
#pragma unroll
        for (int j = 0; j < 4; ++j)
          acc[i][j] = __builtin_amdgcn_mfma_f32_16x16x32_bf16(af[i], bfr[j], acc[i][j], 0, 0, 0);
    }
  }
  const float scale = 0.04419417382415922f;
  __syncthreads();
  unsigned short* Cs = &Sh[0][0];
#pragma unroll
  for (int i = 0; i < 4; ++i)
#pragma unroll
    for (int j = 0; j < 4; ++j)
#pragma unroll
      for (int r = 0; r < 4; ++r) {
        int nl = wn * 64 + i * 16 + lg * 4 + r;
        int ml = wm * 64 + j * 16 + lr;
        Cs[nl * 128 + ml] = f2b(acc[i][j][r] * scale);
      }
  __syncthreads();
  unsigned short* Sb = S + (size_t)b * NP * NP;
#pragma unroll
  for (int it = 0; it < 8; ++it) {
    int chunk = it * 256 + tid;
    int rowl = chunk >> 4, c8 = (chunk & 15) * 8;
    *(bf16x8*)(Sb + (size_t)(n0 + rowl) * NP + m0 + c8) = *(const bf16x8*)(Cs + rowl * 128 + c8);
  }
}

// ---------------------------------------------------------------- sinkhorn via potentials (bf16 S)
__global__ __launch_bounds__(256) void sink_u_kernel(const unsigned short* __restrict__ S,
                                                     const float* __restrict__ v,
                                                     float* __restrict__ u) {
  int t = threadIdx.x, w = t >> 6, lane = t & 63;
  int rowid = blockIdx.x * 4 + w;
  int b = rowid >> 11, i = rowid & 2047;
  const unsigned short* row = S + ((size_t)b * NP + i) * NP;
  const float* vb = v + (size_t)b * NP;
  float m = -INFINITY, s = 0.f;
#pragma unroll
  for (int c = 0; c < 4; ++c) {
    int off = c * 512 + lane * 8;
    bf16x8 x8 = *(const bf16x8*)(row + off);
    float4 va = *(const float4*)(vb + off);
    float4 vc = *(const float4*)(vb + off + 4);
    float xs[8];
    xs[0] = b2f(x8[0]) + va.x; xs[1] = b2f(x8[1]) + va.y;
    xs[2] = b2f(x8[2]) + va.z; xs[3] = b2f(x8[3]) + va.w;
    xs[4] = b2f(x8[4]) + vc.x; xs[5] = b2f(x8[5]) + vc.y;
    xs[6] = b2f(x8[6]) + vc.z; xs[7] = b2f(x8[7]) + vc.w;
    float mc = fmaxf(fmaxf(fmaxf(xs[0], xs[1]), fmaxf(xs[2], xs[3])),
                     fmaxf(fmaxf(xs[4], xs[5]), fmaxf(xs[6], xs[7])));
    float sc = 0.f;
#pragma unroll
    for (int e = 0; e < 8; ++e) sc += __expf(xs[e] - mc);
    float M = fmaxf(m, mc);
    s = s * __expf(m - M) + sc * __expf(mc - M);
    m = M;
  }
#pragma unroll
  for (int st = 1; st < 64; st <<= 1) {
    float m2 = __shfl_xor(m, st), s2 = __shfl_xor(s, st);
    float M = fmaxf(m, m2);
    s = s * __expf(m - M) + s2 * __expf(m2 - M);
    m = M;
  }
  if (lane == 0) {
    float M = fmaxf(m, 0.f);
    float ss = s * __expf(m - M) + __expf(-M);
    u[(size_t)b * NP + i] = -(M + logf(ss));
  }
}

// column partials: 2 cols/thread, 8 row-chunks
__global__ void sink_c1_kernel(const unsigned short* __restrict__ S, const float* __restrict__ u,
                               float* __restrict__ colM, float* __restrict__ colS) {
  int ctile = blockIdx.x, part = blockIdx.y, b = blockIdx.z;
  int t = threadIdx.x, ry = t >> 6, cx = t & 63;
  int c0 = ctile * 128 + cx * 2;
  int rbase = part * 256 + ry * 64;
  const unsigned short* Sb = S + (size_t)b * NP * NP;
  const float* ub = u + (size_t)b * NP;
  float m0 = -INFINITY, s0 = 0.f, m1 = -INFINITY, s1 = 0.f;
  for (int r8 = 0; r8 < 64; r8 += 8) {
    float x0[8], x1[8];
#pragma unroll
    for (int k = 0; k < 8; ++k) {
      int r = rbase + r8 + k;
      unsigned pk = *(const unsigned*)(Sb + (size_t)r * NP + c0);
      float uu = ub[r];
      x0[k] = b2f((unsigned short)pk) + uu;
      x1[k] = b2f((unsigned short)(pk >> 16)) + uu;
    }
    float mc0 = x0[0], mc1 = x1[0];
#pragma unroll
    for (int k = 1; k < 8; ++k) { mc0 = fmaxf(mc0, x0[k]); mc1 = fmaxf(mc1, x1[k]); }
    float sc0 = 0.f, sc1 = 0.f;
#pragma unroll
    for (int k = 0; k < 8; ++k) { sc0 += __expf(x0[k] - mc0); sc1 += __expf(x1[k] - mc1); }
    float M0 = fmaxf(m0, mc0);
    s0 = s0 * __expf(m0 - M0) + sc0 * __expf(mc0 - M0); m0 = M0;
    float M1 = fmaxf(m1, mc1);
    s1 = s1 * __expf(m1 - M1) + sc1 * __expf(mc1 - M1); m1 = M1;
  }
  __shared__ float pm[4][128], ps[4][128];
  pm[ry][cx * 2] = m0; pm[ry][cx * 2 + 1] = m1;
  ps[ry][cx * 2] = s0; ps[ry][cx * 2 + 1] = s1;
  __syncthreads();
  if (t < 128) {
    float m = pm[0][t], s = ps[0][t];
    for (int k = 1; k < 4; ++k) {
      float m2 = pm[k][t], s2 = ps[k][t];
      float M = fmaxf(m, m2);
      s = s * __expf(m - M) + s2 * __expf(m2 - M);
      m = M;
    }
    size_t oo = ((size_t)b * NP + ctile * 128 + t) * 8 + part;
    colM[oo] = m; colS[oo] = s;
  }
}

__global__ void sink_c2_kernel(const float* __restrict__ colM, const float* __restrict__ colS,
                               float* __restrict__ v) {
  int i = blockIdx.x * 256 + threadIdx.x;
  if (i >= BATCH * NP) return;
  float m = -INFINITY, s = 0.f;
  for (int p = 0; p < 8; ++p) {
    float m2 = colM[(size_t)i * 8 + p], s2 = colS[(size_t)i * 8 + p];
    float M = fmaxf(m, m2);
    s = s * __expf(m - M) + s2 * __expf(m2 - M);
    m = M;
  }
  float M = fmaxf(m, 0.f);
  s = s * __expf(m - M) + __expf(-M);
  v[i] = -(M + logf(s));
}

// ---------------------------------------------------------------- perm: wave-per-row, no barriers
__global__ __launch_bounds__(256) void perm_kernel(
    const unsigned short* __restrict__ S, const float* __restrict__ u,
    const float* __restrict__ v, const float* __restrict__ tgt,
    float* __restrict__ outp, float* __restrict__ weights, float* __restrict__ wt) {
  int t = threadIdx.x, w = t >> 6, lane = t & 63;
  int rowid = blockIdx.x * 4 + w;
  int b = rowid >> 11, n = rowid & 2047;
  const unsigned short* row = S + ((size_t)b * NP + n) * NP;
  const float* vb = v + (size_t)b * NP;
  float ui = u[(size_t)b * NP + n];
  float ev[32];
  float lsum = 0.f, lm = -INFINITY;
#pragma unroll
  for (int c = 0; c < 4; ++c) {
    int off = c * 512 + lane * 8;
    bf16x8 x8 = *(const bf16x8*)(row + off);
    float4 va = *(const float4*)(vb + off);
    float4 vc = *(const float4*)(vb + off + 4);
    float e0 = __expf(b2f(x8[0]) + ui + va.x);
    float e1 = __expf(b2f(x8[1]) + ui + va.y);
    float e2 = __expf(b2f(x8[2]) + ui + va.z);
    float e3 = __expf(b2f(x8[3]) + ui + va.w);
    float e4 = __expf(b2f(x8[4]) + ui + vc.x);
    float e5 = __expf(b2f(x8[5]) + ui + vc.y);
    float e6 = __expf(b2f(x8[6]) + ui + vc.z);
    float e7 = __expf(b2f(x8[7]) + ui + vc.w);
    ev[c * 8 + 0] = e0; ev[c * 8 + 1] = e1; ev[c * 8 + 2] = e2; ev[c * 8 + 3] = e3;
    ev[c * 8 + 4] = e4; ev[c * 8 + 5] = e5; ev[c * 8 + 6] = e6; ev[c * 8 + 7] = e7;
    lsum += e0 + e1 + e2 + e3 + e4 + e5 + e6 + e7;
    lm = fmaxf(lm, fmaxf(fmaxf(fmaxf(e0, e1), fmaxf(e2, e3)),
                          fmaxf(fmaxf(e4, e5), fmaxf(e6, e7))));
  }
#pragma unroll
  for (int st = 1; st < 64; st <<= 1) {
    lsum += __shfl_xor(lsum, st);
    lm = fmaxf(lm, __shfl_xor(lm, st));
  }
  float inv = 1.f / (lsum + 1e-8f);
  // write pn + accumulate weighted-tgt partials
  const float* tb = tgt + (size_t)b * 3 * NP;
  float* op = outp + ((size_t)b * NP + n) * NP;
  float av0 = 0.f, av1 = 0.f, av2 = 0.f;
#pragma unroll
  for (int c = 0; c < 4; ++c) {
    int off = c * 512 + lane * 8;
    float p0 = ev[c * 8 + 0] * inv, p1 = ev[c * 8 + 1] * inv;
    float p2 = ev[c * 8 + 2] * inv, p3 = ev[c * 8 + 3] * inv;
    float p4 = ev[c * 8 + 4] * inv, p5 = ev[c * 8 + 5] * inv;
    float p6 = ev[c * 8 + 6] * inv, p7 = ev[c * 8 + 7] * inv;
    float4 o0 = {p0, p1, p2, p3};
    float4 o1 = {p4, p5, p6, p7};
    *(float4*)(op + off) = o0;
    *(float4*)(op + off + 4) = o1;
    float4 t0a = *(const float4*)(tb + off);
    float4 t0b = *(const float4*)(tb + off + 4);
    av0 += p0 * t0a.x + p1 * t0a.y + p2 * t0a.z + p3 * t0a.w +
           p4 * t0b.x + p5 * t0b.y + p6 * t0b.z + p7 * t0b.w;
    float4 t1a = *(const float4*)(tb + NP + off);
    float4 t1b = *(const float4*)(tb + NP + off + 4);
    av1 += p0 * t1a.x + p1 * t1a.y + p2 * t1a.z + p3 * t1a.w +
           p4 * t1b.x + p5 * t1b.y + p6 * t1b.z + p7 * t1b.w;
    float4 t2a = *(const float4*)(tb + 2 * NP + off);
    float4 t2b = *(const float4*)(tb + 2 * NP + off + 4);
    av2 += p0 * t2a.x + p1 * t2a.y + p2 * t2a.z + p3 * t2a.w +
           p4 * t2b.x + p5 * t2b.y + p6 * t2b.z + p7 * t2b.w;
  }
#pragma unroll
  for (int st = 1; st < 64; st <<= 1) {
    av0 += __shfl_xor(av0, st);
    av1 += __shfl_xor(av1, st);
    av2 += __shfl_xor(av2, st);
  }
  if (lane == 0) {
    wt[((size_t)b * 3 + 0) * NP + n] = av0;
    wt[((size_t)b * 3 + 1) * NP + n] = av1;
    wt[((size_t)b * 3 + 2) * NP + n] = av2;
    weights[(size_t)b * NP + n] = lm;
  }
}

// ---------------------------------------------------------------- 3x3 Kabsch helpers (fp64)
__device__ double det3d(const double M[3][3]) {
  return M[0][0] * (M[1][1] * M[2][2] - M[1][2] * M[2][1])
       - M[0][1] * (M[1][0] * M[2][2] - M[1][2] * M[2][0])
       + M[0][2] * (M[1][0] * M[2][1] - M[1][1] * M[2][0]);
}

#define JROT(p, q)                                                              \
  do {                                                                          \
    double apq = S[p][q];                                                       \
    if (fabs(apq) > 1e-60) {                                                    \
      double tau = (S[q][q] - S[p][p]) / (2.0 * apq);                           \
      double tt = (tau >= 0.0) ? 1.0 / (tau + sqrt(1.0 + tau * tau))            \
                               : 1.0 / (tau - sqrt(1.0 + tau * tau));           \
      double cr = 1.0 / sqrt(1.0 + tt * tt), sr = tt * cr;                      \
      _Pragma("unroll") for (int k = 0; k < 3; ++k) {                           \
        double skp = S[k][p], skq = S[k][q];                                    \
        S[k][p] = cr * skp - sr * skq;  S[k][q] = sr * skp + cr * skq;          \
      }                                                                         \
      _Pragma("unroll") for (int k = 0; k < 3; ++k) {                           \
        double spk = S[p][k], sqk = S[q][k];                                    \
        S[p][k] = cr * spk - sr * sqk;  S[q][k] = sr * spk + cr * sqk;          \
      }                                                                         \
      _Pragma("unroll") for (int k = 0; k < 3; ++k) {                           \
        double vkp = V[k][p], vkq = V[k][q];                                    \
        V[k][p] = cr * vkp - sr * vkq;  V[k][q] = sr * vkp + cr * vkq;          \
      }                                                                         \
    }                                                                           \
  } while (0)

#define CSWAPCOL(i, j, ei, ej)                                                  \
  if (ei < ej) {                                                                \
    double tt_ = ei; ei = ej; ej = tt_;                                         \
    _Pragma("unroll") for (int r = 0; r < 3; ++r) {                             \
      double tv = V[r][i]; V[r][i] = V[r][j]; V[r][j] = tv;                     \
    }                                                                           \
  }

// ---------------------------------------------------------------- cent+Hm+Kabsch fused (1 block per batch)
__global__ __launch_bounds__(256) void cent_hm_solve_kernel(
    const float* __restrict__ src, const float* __restrict__ wt,
    const float* __restrict__ weights, float* __restrict__ out) {
  int b = blockIdx.x, t = threadIdx.x;
  int w = t >> 6, lane = t & 63;
  __shared__ float xr[4][16];
  const float* sb = src + (size_t)b * 3 * NP;
  const float* wb = wt + (size_t)b * 3 * NP;
  const float* ww = weights + (size_t)b * NP;
  float lw[8], ls0[8], ls1[8], ls2[8], lt0[8], lt1[8], lt2[8];
#pragma unroll
  for (int i = 0; i < 8; ++i) {
    int n = t + i * 256;
    lw[i] = ww[n];
    ls0[i] = sb[n]; ls1[i] = sb[NP + n]; ls2[i] = sb[2 * NP + n];
    lt0[i] = wb[n]; lt1[i] = wb[NP + n]; lt2[i] = wb[2 * NP + n];
  }
  // phase 1: wsum
  float s = 0.f;
#pragma unroll
  for (int i = 0; i < 8; ++i) s += lw[i];
#pragma unroll
  for (int st = 1; st < 64; st <<= 1) s += __shfl_xor(s, st);
  if (lane == 0) xr[w][0] = s;
  __syncthreads();
  float wsum = xr[0][0] + xr[1][0] + xr[2][0] + xr[3][0];
  float inv = 1.f / (wsum + 1e-8f);
  // phase 2: 6 weighted centroids
  float a[6] = {};
#pragma unroll
  for (int i = 0; i < 8; ++i) {
    float wv = lw[i] * inv;
    a[0] += ls0[i] * wv; a[1] += ls1[i] * wv; a[2] += ls2[i] * wv;
    a[3] += lt0[i] * wv; a[4] += lt1[i] * wv; a[5] += lt2[i] * wv;
  }
#pragma unroll
  for (int k = 0; k < 6; ++k)
#pragma unroll
    for (int st = 1; st < 64; st <<= 1) a[k] += __shfl_xor(a[k], st);
  __syncthreads();
  if (lane == 0) {
#pragma unroll
    for (int k = 0; k < 6; ++k) xr[w][k] = a[k];
  }
  __syncthreads();
  float cc[6];
#pragma unroll
  for (int k = 0; k < 6; ++k) cc[k] = xr[0][k] + xr[1][k] + xr[2][k] + xr[3][k];
  // phase 3: 9 covariance entries
  float h[9] = {};
#pragma unroll
  for (int i = 0; i < 8; ++i) {
    float wv = lw[i] * inv;
    float s0 = ls0[i] - cc[0], s1 = ls1[i] - cc[1], s2 = ls2[i] - cc[2];
    float d0 = (lt0[i] - cc[3]) * wv, d1 = (lt1[i] - cc[4]) * wv, d2 = (lt2[i] - cc[5]) * wv;
    h[0] += s0 * d0; h[1] += s0 * d1; h[2] += s0 * d2;
    h[3] += s1 * d0; h[4] += s1 * d1; h[5] += s1 * d2;
    h[6] += s2 * d0; h[7] += s2 * d1; h[8] += s2 * d2;
  }
#pragma unroll
  for (int k = 0; k < 9; ++k)
#pragma unroll
    for (int st = 1; st < 64; st <<= 1) h[k] += __shfl_xor(h[k], st);
  __syncthreads();
  if (lane == 0) {
#pragma unroll
    for (int k = 0; k < 9; ++k) xr[w][k] = h[k];
  }
  __syncthreads();
  if (t == 0) {
    float hm9[9];
#pragma unroll
    for (int k = 0; k < 9; ++k) hm9[k] = xr[0][k] + xr[1][k] + xr[2][k] + xr[3][k];
    double A[3][3];
#pragma unroll
    for (int r = 0; r < 3; ++r)
#pragma unroll
      for (int c = 0; c < 3; ++c) A[r][c] = (double)hm9[r * 3 + c];
    double S[3][3];
#pragma unroll
    for (int i = 0; i < 3; ++i)
#pragma unroll
      for (int j = 0; j < 3; ++j) {
        double acc = 0.0;
#pragma unroll
        for (int k = 0; k < 3; ++k) acc += A[k][i] * A[k][j];
        S[i][j] = acc;
      }
    double V[3][3] = {{1, 0, 0}, {0, 1, 0}, {0, 0, 1}};
    for (int sweep = 0; sweep < 12; ++sweep) {
      JROT(0, 1); JROT(0, 2); JROT(1, 2);
    }
    double e0 = S[0][0], e1 = S[1][1], e2 = S[2][2];
    CSWAPCOL(0, 1, e0, e1);
    CSWAPCOL(0, 2, e0, e2);
    CSWAPCOL(1, 2, e1, e2);
    double Us[3][3];
#pragma unroll
    for (int i = 0; i < 3; ++i) {
      double v0 = V[0][i], v1 = V[1][i], v2 = V[2][i];
      double u0 = A[0][0] * v0 + A[0][1] * v1 + A[0][2] * v2;
      double u1 = A[1][0] * v0 + A[1][1] * v1 + A[1][2] * v2;
      double u2 = A[2][0] * v0 + A[2][1] * v1 + A[2][2] * v2;
      double nrm = sqrt(u0 * u0 + u1 * u1 + u2 * u2);
      if (nrm > 1e-30) { u0 /= nrm; u1 /= nrm; u2 /= nrm; }
      else if (i == 2) {
        u0 = Us[1][0] * Us[2][1] - Us[2][0] * Us[1][1];
        u1 = Us[2][0] * Us[0][1] - Us[0][0] * Us[2][1];
        u2 = Us[0][0] * Us[1][1] - Us[1][0] * Us[0][1];
        double nn = sqrt(u0 * u0 + u1 * u1 + u2 * u2);
        if (nn > 1e-30) { u0 /= nn; u1 /= nn; u2 /= nn; }
      }
      Us[0][i] = u0; Us[1][i] = u1; Us[2][i] = u2;
    }
    double d = det3d(V) * det3d(Us);
    double R[3][3];
#pragma unroll
    for (int i = 0; i < 3; ++i)
#pragma unroll
      for (int j = 0; j < 3; ++j)
        R[i][j] = V[i][0] * Us[j][0] + V[i][1] * Us[j][1] + d * V[i][2] * Us[j][2];
    double sc[3] = {(double)cc[0], (double)cc[1], (double)cc[2]};
    double tc[3] = {(double)cc[3], (double)cc[4], (double)cc[5]};
#pragma unroll
    for (int r = 0; r < 3; ++r)
#pragma unroll
      for (int c = 0; c < 3; ++c) out[b * 9 + r * 3 + c] = (float)R[r][c];
#pragma unroll
    for (int i = 0; i < 3; ++i) {
      double tv = tc[i] - (R[i][0] * sc[0] + R[i][1] * sc[1] + R[i][2] * sc[2]);
      out[36 + b * 3 + i] = (float)tv;
    }
  }
}

// ---------------------------------------------------------------- launch
extern "C" void kernel_launch(void* const* d_in, const int* in_sizes, int n_in,
                              void* d_out, int out_size, void* d_ws, size_t ws_size,
                              hipStream_t stream) {
  const float* src  = (const float*)d_in[0];
  const float* tgt  = (const float*)d_in[1];
  const float* g_w1 = (const float*)d_in[2];
  const float* g_s1 = (const float*)d_in[3];
  const float* g_b1 = (const float*)d_in[4];
  const float* g_w2 = (const float*)d_in[5];
  const float* g_s2 = (const float*)d_in[6];
  const float* g_b2 = (const float*)d_in[7];
  const float* g_wo = (const float*)d_in[8];
  const float* g_so = (const float*)d_in[9];
  const float* g_bo = (const float*)d_in[10];
  const float* q_w  = (const float*)d_in[11];
  const float* q_b  = (const float*)d_in[12];
  const float* k_w  = (const float*)d_in[13];
  const float* k_b  = (const float*)d_in[14];
  const float* v_w  = (const float*)d_in[15];
  const float* v_b  = (const float*)d_in[16];
  const float* m_w  = (const float*)d_in[17];
  const float* m_b  = (const float*)d_in[18];
  const float* mlp_w = (const float*)d_in[19];
  float* out = (float*)d_out;
  float* ws = (float*)d_ws;

  const size_t SLOT = 4194304;  // 16 MB slots (in floats)
  unsigned short* d0t  = (unsigned short*)(ws + 0 * SLOT);
  unsigned short* d1t  = (unsigned short*)(ws + 1 * SLOT);
  unsigned short* Q0   = (unsigned short*)(ws + 2 * SLOT);
  unsigned short* K0   = (unsigned short*)(ws + 3 * SLOT);
  unsigned short* V0   = (unsigned short*)(ws + 4 * SLOT);
  unsigned short* Q1   = (unsigned short*)(ws + 5 * SLOT);
  unsigned short* K1   = (unsigned short*)(ws + 6 * SLOT);
  unsigned short* V1   = (unsigned short*)(ws + 7 * SLOT);
  unsigned short* att0t = (unsigned short*)(ws + 8 * SLOT);
  unsigned short* att1t = (unsigned short*)(ws + 9 * SLOT);
  unsigned short* mp0t = Q0;
  unsigned short* mp1t = Q1;
  unsigned short* d0nt = att0t;
  unsigned short* d1nt = att1t;
  unsigned short* base3  = (unsigned short*)(ws + 3 * SLOT);
  unsigned short* q_wb   = base3 + 4456448;
  unsigned short* k_wb   = q_wb + 262144;
  unsigned short* v_wb   = k_wb + 262144;
  unsigned short* m_wb   = v_wb + 262144;
  unsigned short* mlp_wb = m_wb + 262144;
  unsigned short* w2b    = mlp_wb + 524288;
  unsigned short* wob    = w2b + 8192;
  unsigned short* xcg    = att0t;  // dead before attention
  unsigned short* SbU = (unsigned short*)ws;  // bf16 S (B,NP,NP): slots 0..2 (dead after mlp)
  int*   idx0 = (int*)(ws + 10 * SLOT);
  int*   idx1 = idx0 + BATCH * NP * KNNK;
  float* colM = ws + 10 * SLOT + 327680;
  float* colS = colM + BATCH * NP * 8;
  float* weights = colS + BATCH * NP * 8;
  float* wsum = weights + BATCH * NP;
  float* wtg  = wsum + BATCH;
  float* cent = wtg + BATCH * 3 * NP;
  float* Hmb  = cent + BATCH * 6;
  float* upot = Hmb + BATCH * 9;
  float* vpot = upot + BATCH * NP;

  // 0+1. merged kNN + weight conversions + vpot zero (one dispatch)
  convknn_kernel<<<4096 + 1648, 256, 0, stream>>>(src, tgt, idx0, idx1,
                                                  q_w, k_w, v_w, m_w, mlp_w, g_w2, g_wo,
                                                  q_wb, k_wb, v_wb, m_wb, mlp_wb, w2b, wob, vpot);
  // 2. GAC -> xcg -> d0t/d1t
  gac4_kernel<<<2 * BATCH * NP / 4, 256, 0, stream>>>(src, tgt, idx0, idx1, g_w1, g_s1, g_b1,
                                                      w2b, g_s2, g_b2, xcg);
  dim3 gg(2 * BATCH * NP / 128, DEMB / 128);
  gacproj_kernel<<<gg, 256, 0, stream>>>(wob, g_so, g_bo, xcg, d0t, d1t);
  // 3. Q/K/V projections (merged 6-in-1; Q pre-scaled)
  dim3 gqkv(NP / 128, DEMB / 128, 24);
  qkv_kernel<<<gqkv, 256, 0, stream>>>(q_wb, k_wb, v_wb, q_b, k_b, v_b, d0t, d1t,
                                       Q0, K0, V0, Q1, K1, V1);
  // 4. cross attention (R13-proven)
  attn_mfma_kernel<<<2 * 16 * 16, 256, 0, stream>>>(Q0, K0, V0, Q1, K1, V1, att0t, att1t);
  // 5. message projection (both sides, one dispatch)
  dim3 gq8(NP / 128, DEMB / 128, 8);
  proj_mfma_kernel<3, 512><<<gq8, 256, 0, stream>>>(m_wb, m_b, att0t, att1t, nullptr, nullptr,
                                                    nullptr, nullptr, mp0t, mp1t);
  // 6. MLP + residual (both sides, one dispatch)
  proj_mfma_kernel<4, 1024><<<gq8, 256, 0, stream>>>(mlp_wb, nullptr, d0t, d1t, mp0t, mp1t,
                                                     d0t, d1t, d0nt, d1nt);
  // 7. dists -> bf16 S
  dists_mfma_kernel<<<dim3(NP / 128, NP / 128, BATCH), 256, 0, stream>>>(d0nt, d1nt, SbU);
  // 8. sinkhorn via potentials, 5 iterations (separate c2: dispatch boundary beats fences)
  for (int it = 0; it < 5; ++it) {
    sink_u_kernel<<<BATCH * NP / 4, 256, 0, stream>>>(SbU, vpot, upot);
    sink_c1_kernel<<<dim3(NP / 128, 8, BATCH), 256, 0, stream>>>(SbU, upot, colM, colS);
    sink_c2_kernel<<<(BATCH * NP + 255) / 256, 256, 0, stream>>>(colM, colS, vpot);
  }
  // 9. perm_norm (to out) + weights + weighted_tgt (wave-per-row, barrier-free)
  perm_kernel<<<BATCH * NP / 4, 256, 0, stream>>>(SbU, upot, vpot, tgt, out + 48, weights, wtg);
  // 10. Kabsch fully fused (cent+Hm+solve, 1 block/batch)
  cent_hm_solve_kernel<<<BATCH, 256, 0, stream>>>(src, wtg, weights, out);
}